// Round 18
// baseline (533.411 us; speedup 1.0000x reference)
//
#include <hip/hip_runtime.h>
#include <hip/hip_bf16.h>

// NeuralFieldCosmo — R18: resurrect R8's 32-edge-tile / v_mfma_f32_32x32x8_bf16
// formulation. R8's NaN is now attributed to the hand-rolled cvt_pk asm
// (R10 isolated it; banned), NOT the 32x32 layout. This round swaps in the
// R16-verified library pack (packc) and keeps R17's plumbing verbatim.
// Single unverified variable: the 32x32x8 A/B k-map (row=lane&31,
// k=4*(lane>>5)+j) — analogous to the R4-R17-verified 16x16 map. C/D layout
// (col=lane&31, row=(r&3)+8(r>>2)+4(lane>>5)) is hardware-verified (m74/m101).
// Payoff per 32 edges: shfl 80->20, ds_read_b128 32->16, MFMA instr 72->36.
// Ledger: raw cvt_pk asm banned (R8/R9/R10). f2bf + packc verified.
// launch_bounds(256,2) + consts in LDS = spill-free at <=128 VGPR; spill
// tell = FETCH > 100 MB. Kill-rule: absmax>=0.15 -> layout wrong -> revert R17.

typedef __attribute__((ext_vector_type(4)))  short    short4v;  // 4 bf16 (2 VGPR)
typedef __attribute__((ext_vector_type(4)))  float    float4v;
typedef __attribute__((ext_vector_type(16))) float    f32x16;
typedef __attribute__((ext_vector_type(4)))  unsigned uint4v;
typedef __attribute__((ext_vector_type(2)))  unsigned uint2v;

constexpr float LN_EPS   = 1e-5f;
constexpr float LOG2E_X2 = 2.8853900817779268f;  // 2*log2(e)

// RNE float -> bf16 bits (staging; verified R4-R17)
__device__ __forceinline__ unsigned f2bf(float x) {
  unsigned u = __builtin_bit_cast(unsigned, x);
  u += 0x7FFFu + ((u >> 16) & 1u);
  return u >> 16;
}
__device__ __forceinline__ unsigned pack2(float lo, float hi) {
  return f2bf(lo) | (f2bf(hi) << 16);
}
// HOT pack: library bf16x2 cvt (RNE), low 16 bits = lo. Verified R16/R17.
__device__ __forceinline__ unsigned packc(float lo, float hi) {
  float2 v; v.x = lo; v.y = hi;
  const __hip_bfloat162 b = __float22bfloat162_rn(v);
  static_assert(sizeof(__hip_bfloat162) == 4, "bf16x2 must be 4 bytes");
  unsigned r;
  __builtin_memcpy(&r, &b, 4);
  return r;
}
__device__ __forceinline__ float bflo2f(unsigned u) {
  return __builtin_bit_cast(float, u << 16);
}
__device__ __forceinline__ float bfhi2f(unsigned u) {
  return __builtin_bit_cast(float, u & 0xFFFF0000u);
}
// rcp(exp2(x)+1)
__device__ __forceinline__ float sigm2(float x) {
  return __builtin_amdgcn_rcpf(__builtin_amdgcn_exp2f(x) + 1.0f);
}

__device__ __forceinline__ f32x16 mfma32(short4v a, short4v b, f32x16 c) {
#if __has_builtin(__builtin_amdgcn_mfma_f32_32x32x8bf16_1k)
  return __builtin_amdgcn_mfma_f32_32x32x8bf16_1k(a, b, c, 0, 0, 0);
#else
  asm volatile("v_mfma_f32_32x32x8_bf16 %0, %1, %2, %0\n\ts_nop 7\n\ts_nop 7"
               : "+v"(c) : "v"(a), "v"(b));
  return c;
#endif
}

// LN over 32 chs (16/lane; partner lane^32 holds complement), affine (packed
// bf16 pairs), relu, pack to 4 B-frag K-segments. hv idx s*4+j <-> ch 8s+4h+j.
__device__ __forceinline__ void ln_relu_pack32(const float* hv, const unsigned* gp,
                                               const unsigned* bp, short4v* bh) {
  float sum = 0.f, ss = 0.f;
#pragma unroll
  for (int i = 0; i < 16; ++i) { sum += hv[i]; ss += hv[i] * hv[i]; }
  sum += __shfl_xor(sum, 32);
  ss  += __shfl_xor(ss, 32);
  const float m   = sum * (1.0f / 32.0f);
  const float var = fmaxf(ss * (1.0f / 32.0f) - m * m, 0.f);
  const float rs  = rsqrtf(var + LN_EPS);
#pragma unroll
  for (int s = 0; s < 4; ++s) {
    float y[4];
#pragma unroll
    for (int p = 0; p < 2; ++p) {
      const unsigned g = gp[s * 2 + p], b = bp[s * 2 + p];
      y[2 * p]     = fmaxf((hv[s * 4 + 2 * p]     - m) * rs * bflo2f(g) + bflo2f(b), 0.f);
      y[2 * p + 1] = fmaxf((hv[s * 4 + 2 * p + 1] - m) * rs * bfhi2f(g) + bfhi2f(b), 0.f);
    }
    uint2v u; u[0] = packc(y[0], y[1]); u[1] = packc(y[2], y[3]);
    bh[s] = __builtin_bit_cast(short4v, u);
  }
}

// ---------------- CSR build (R17-verified) ----------------

__global__ void nf_hist(const int* __restrict__ out_edges, int* __restrict__ counts, int E) {
  const int t4 = (blockIdx.x * blockDim.x + threadIdx.x) * 4;
  if (t4 + 3 < E) {
    const int4 v = *(const int4*)(out_edges + t4);
    atomicAdd(&counts[v.x], 1);
    atomicAdd(&counts[v.y], 1);
    atomicAdd(&counts[v.z], 1);
    atomicAdd(&counts[v.w], 1);
  } else {
    for (int i = t4; i < E; ++i) atomicAdd(&counts[out_edges[i]], 1);
  }
}

__global__ void nf_alloc(const int* __restrict__ counts, int* __restrict__ offsets,
                         int* __restrict__ cursor, int* __restrict__ total, int N) {
  const int i = blockIdx.x * blockDim.x + threadIdx.x;
  const int lane = threadIdx.x & 63;
  int c = (i < N) ? counts[i] : 0;
  int sc = c;
#pragma unroll
  for (int d = 1; d < 64; d <<= 1) {
    int v = __shfl_up(sc, d);
    if (lane >= d) sc += v;
  }
  const int excl = sc - c;
  const int wtot = __shfl(sc, 63);
  int base = 0;
  if (lane == 0) base = atomicAdd(total, wtot);
  base = __shfl(base, 0);
  if (i < N) {
    offsets[i] = base + excl;
    cursor[i]  = base + excl;
  }
}

// ---------------- main compute ----------------
// SCATTER_MODE: 0 = CSR-ordered bf16 stream, 1 = direct f32 atomics fallback

template <int SCATTER_MODE>
__global__ __launch_bounds__(256, 2)   // cap 256: never spill (R3-R17 proven)
void nf_main(const int* __restrict__ in_edges,
             const int* __restrict__ out_edges,
             const float* __restrict__ ef,
             const float* __restrict__ coords,
             const float* __restrict__ W1, const float* __restrict__ b1,
             const float* __restrict__ g1, const float* __restrict__ be1,
             const float* __restrict__ W2, const float* __restrict__ b2,
             const float* __restrict__ g2, const float* __restrict__ be2,
             const float* __restrict__ W3, const float* __restrict__ b3,
             void* __restrict__ out_ch,   // mode0: unsigned[E][8] bf16x2 ; mode1: float sums (d_out)
             int* __restrict__ aux,       // mode1: counts
             int* __restrict__ cursor,    // mode0: [N]
             int E, int ntiles)
{
  // W3 A-frags (prescaled 2log2e): [mt][blk][lane][4 u32]  (16 KB)
  __shared__ __align__(16) unsigned sA3[8 * 2 * 64 * 4];
  __shared__ __align__(16) float    sB3f[256];     // 2log2e*b3, [o][i]
  // per-h packed consts: [0..23] w1 (d*8+sp), [24..31] b1,
  // [32..39] g1, [40..47] be1, [48..55] g2, [56..63] be2
  __shared__ __align__(16) unsigned sK[2][64];
  __shared__ __align__(16) float    sB2f[2][16];   // b2 in C-row order

  const int t    = threadIdx.x;
  const int l    = t & 63;
  const int h    = l >> 5;     // half: k-group / C-row group
  const int ecol = l & 31;     // edge column within 32-edge tile

  // ---- one-time LDS staging ----
#pragma unroll
  for (int rep = 0; rep < 16; ++rep) {
    const int idx = rep * 256 + t;
    const int u = idx & 3, ll = (idx >> 2) & 63, b = (idx >> 8) & 1, mt = idx >> 9;
    const int s = b * 2 + (u >> 1), jp = u & 1;
    const int hh = ll >> 5, m = ll & 31;
    const int o = 2 * mt + (m >> 4), i = m & 15;
    const int k0 = 8 * s + 4 * hh + 2 * jp;
    sA3[idx] = pack2(LOG2E_X2 * W3[(size_t)k0 * 256 + o * 16 + i],
                     LOG2E_X2 * W3[(size_t)(k0 + 1) * 256 + o * 16 + i]);
  }
  sB3f[t] = LOG2E_X2 * b3[t];
  if (t < 128) {
    const int hh = t >> 6, i = t & 63;
    const int sp = i & 7;
    const int ch = 8 * (sp >> 1) + 4 * hh + 2 * (sp & 1);
    if (i < 24) {
      const int d = i >> 3;
      sK[hh][i] = pack2(W1[d * 32 + ch], W1[d * 32 + ch + 1]);
    } else {
      const float* src = (i < 32) ? b1 : (i < 40) ? g1 : (i < 48) ? be1
                        : (i < 56) ? g2 : be2;
      sK[hh][i] = pack2(src[ch], src[ch + 1]);
    }
  }
  if (t < 32) {
    const int hh = t >> 4, r = t & 15;
    sB2f[hh][r] = b2[(r & 3) + 8 * (r >> 2) + 4 * hh];
  }

  // L2 A-frags in regs (8 VGPR): A[m=ch_out=ecol][k=8s+4h+j] = W2[k][ecol]
  short4v a2[4];
#pragma unroll
  for (int s = 0; s < 4; ++s) {
    short4v v;
#pragma unroll
    for (int j = 0; j < 4; ++j)
      v[j] = (short)f2bf(W2[(8 * s + 4 * h + j) * 32 + ecol]);
    a2[s] = v;
  }
  __syncthreads();

  const int gwave  = (blockIdx.x * blockDim.x + t) >> 6;
  const int nwaves = (gridDim.x * blockDim.x) >> 6;

  // ---- prologue: tile-0 state ----
  int tile = gwave;
  bool valid = false; int oe = 0;
  float x0 = 0.f, x1 = 0.f, x2 = 0.f;
  float4v f4a = {}, f4b = {};
  if (tile < ntiles) {
    const int eIdx = tile * 32 + ecol;
    valid = eIdx < E;
    const int eS = valid ? eIdx : 0;
    const int ie = in_edges[eS]; oe = out_edges[eS];
    x0 = coords[3 * eS]; x1 = coords[3 * eS + 1]; x2 = coords[3 * eS + 2];
    f4a = *(const float4v*)(ef + (size_t)ie * 16 + 4 * h);
    f4b = *(const float4v*)(ef + (size_t)ie * 16 + 8 + 4 * h);
  }

  for (; tile < ntiles; tile += nwaves) {
    // ---- prefetch next tile indices + coords ----
    const int tn = tile + nwaves;
    int ieN = 0, oeN = 0; bool validN = false;
    float x0N = 0.f, x1N = 0.f, x2N = 0.f;
    if (tn < ntiles) {
      const int eIdxN = tn * 32 + ecol;
      validN = eIdxN < E;
      const int eSN = validN ? eIdxN : 0;
      ieN = in_edges[eSN]; oeN = out_edges[eSN];
      x0N = coords[3 * eSN]; x1N = coords[3 * eSN + 1]; x2N = coords[3 * eSN + 2];
    }

    // CSR slot (atomic latency hides under MLP)
    int pos = 0;
    if (SCATTER_MODE == 0 && h == 0 && valid)
      pos = atomicAdd(&cursor[oe], 1);

    // ---- L1: 3 -> 32 (16 chs/lane; consts via h-broadcast LDS) ----
    float hv[16];
    {
      const uint4v* kk = (const uint4v*)&sK[h][0];
      const uint4v b1a = kk[6], b1b = kk[7];
#pragma unroll
      for (int sp = 0; sp < 8; ++sp) {
        const unsigned ub = (sp < 4) ? b1a[sp] : b1b[sp - 4];
        const int base = (sp >> 1) * 4 + (sp & 1) * 2;
        hv[base]     = bflo2f(ub);
        hv[base + 1] = bfhi2f(ub);
      }
#pragma unroll
      for (int d = 0; d < 3; ++d) {
        const uint4v wa = kk[d * 2], wb = kk[d * 2 + 1];
        const float xd = (d == 0) ? x0 : (d == 1) ? x1 : x2;
#pragma unroll
        for (int sp = 0; sp < 8; ++sp) {
          const unsigned uw = (sp < 4) ? wa[sp] : wb[sp - 4];
          const int base = (sp >> 1) * 4 + (sp & 1) * 2;
          hv[base]     = fmaf(xd, bflo2f(uw), hv[base]);
          hv[base + 1] = fmaf(xd, bfhi2f(uw), hv[base + 1]);
        }
      }
    }
    short4v bh[4];
    {
      unsigned lnc[16];
      const uint4v* kg = (const uint4v*)&sK[h][32];
#pragma unroll
      for (int r4 = 0; r4 < 4; ++r4) {
        const uint4v v = kg[r4];
        lnc[r4 * 4 + 0] = v[0]; lnc[r4 * 4 + 1] = v[1];
        lnc[r4 * 4 + 2] = v[2]; lnc[r4 * 4 + 3] = v[3];
      }
      ln_relu_pack32(hv, &lnc[0], &lnc[8], bh);
    }

    // ---- L2 GEMM: 32 -> 32 (one 32x32 tile, K=32 via 4 segments) ----
    f32x16 c;
    {
      const float4v* bb = (const float4v*)&sB2f[h][0];
      const float4v c0 = bb[0], c1 = bb[1], c2 = bb[2], c3i = bb[3];
#pragma unroll
      for (int e = 0; e < 4; ++e) {
        c[e] = c0[e]; c[4 + e] = c1[e]; c[8 + e] = c2[e]; c[12 + e] = c3i[e];
      }
    }
#pragma unroll
    for (int s = 0; s < 4; ++s) c = mfma32(a2[s], bh[s], c);

    {
      float hv2[16];
#pragma unroll
      for (int r = 0; r < 16; ++r) hv2[r] = c[r];
      unsigned ln2[16];
      const uint4v* kg2 = (const uint4v*)&sK[h][48];
#pragma unroll
      for (int r4 = 0; r4 < 4; ++r4) {
        const uint4v v = kg2[r4];
        ln2[r4 * 4 + 0] = v[0]; ln2[r4 * 4 + 1] = v[1];
        ln2[r4 * 4 + 2] = v[2]; ln2[r4 * 4 + 3] = v[3];
      }
      ln_relu_pack32(hv2, &ln2[0], &ln2[8], bh);
    }

    // ---- prefetch next tile's feature gather (ieN landed) ----
    float4v f4aN = {}, f4bN = {};
    if (tn < ntiles) {
      f4aN = *(const float4v*)(ef + (size_t)ieN * 16 + 4 * h);
      f4bN = *(const float4v*)(ef + (size_t)ieN * 16 + 8 + 4 * h);
    }

    // lane-half partial of sum_i f[i] (completed by the pr shfl_xor(32))
    const float sumf = (f4a[0] + f4a[1]) + (f4a[2] + f4a[3])
                     + (f4b[0] + f4b[1]) + (f4b[2] + f4b[3]);

    // ---- L3: 8 m-tiles (2 o's each), K=32; tanh-algebra epilogue ----
#pragma unroll
    for (int mt = 0; mt < 8; ++mt) {
      const uint4v av0 = *(const uint4v*)&sA3[mt * 512 + (l << 2)];
      const uint4v av1 = *(const uint4v*)&sA3[mt * 512 + 256 + (l << 2)];
      f32x16 c3;
      {
        const float4v i0 = *(const float4v*)&sB3f[(2 * mt) * 16 + 4 * h];
        const float4v i1 = *(const float4v*)&sB3f[(2 * mt) * 16 + 8 + 4 * h];
        const float4v i2 = *(const float4v*)&sB3f[(2 * mt + 1) * 16 + 4 * h];
        const float4v i3 = *(const float4v*)&sB3f[(2 * mt + 1) * 16 + 8 + 4 * h];
#pragma unroll
        for (int e = 0; e < 4; ++e) {
          c3[e] = i0[e]; c3[4 + e] = i1[e]; c3[8 + e] = i2[e]; c3[12 + e] = i3[e];
        }
      }
      uint2v u01, u23;
      u01[0] = av0[0]; u01[1] = av0[1];  u23[0] = av0[2]; u23[1] = av0[3];
      c3 = mfma32(__builtin_bit_cast(short4v, u01), bh[0], c3);
      c3 = mfma32(__builtin_bit_cast(short4v, u23), bh[1], c3);
      u01[0] = av1[0]; u01[1] = av1[1];  u23[0] = av1[2]; u23[1] = av1[3];
      c3 = mfma32(__builtin_bit_cast(short4v, u01), bh[2], c3);
      c3 = mfma32(__builtin_bit_cast(short4v, u23), bh[3], c3);

      float dot0 = 0.f, dot1 = 0.f;
#pragma unroll
      for (int j = 0; j < 4; ++j) {
        dot0 = fmaf(f4a[j], sigm2(c3[j]),      dot0);
        dot0 = fmaf(f4b[j], sigm2(c3[4 + j]),  dot0);
        dot1 = fmaf(f4a[j], sigm2(c3[8 + j]),  dot1);
        dot1 = fmaf(f4b[j], sigm2(c3[12 + j]), dot1);
      }
      float pr0 = fmaf(-2.0f, dot0, sumf);
      float pr1 = fmaf(-2.0f, dot1, sumf);
      pr0 += __shfl_xor(pr0, 32);
      pr1 += __shfl_xor(pr1, 32);

      if (SCATTER_MODE == 0) {
        if (h == 0 && valid)
          ((unsigned*)out_ch)[(size_t)pos * 8 + mt] = packc(pr0, pr1);
      } else {
        if (h == 0 && valid) {
          float* sums = (float*)out_ch;
          atomicAdd(&sums[(size_t)oe * 16 + 2 * mt],     pr0);
          atomicAdd(&sums[(size_t)oe * 16 + 2 * mt + 1], pr1);
        }
      }
    }
    if (SCATTER_MODE == 1) {
      if (h == 0 && valid) atomicAdd(&aux[oe], 1);
    }

    // rotate pipeline state
    valid = validN; oe = oeN;
    x0 = x0N; x1 = x1N; x2 = x2N; f4a = f4aN; f4b = f4bN;
  }
}

// ---------------- per-node reduce (CSR path, bf16 rows; R17-verified) ----------------

__global__ __launch_bounds__(256)
void nf_reduce(const uint4v* __restrict__ out_chb4, const int* __restrict__ counts,
               const int* __restrict__ offsets, float* __restrict__ out, int N) {
  const int gid  = blockIdx.x * 128 + (threadIdx.x >> 1);  // node
  const int half = threadIdx.x & 1;                        // channels 8h..8h+7
  if (gid >= N) return;
  const int deg = counts[gid];
  const int off = offsets[gid];
  float a[8] = {0.f, 0.f, 0.f, 0.f, 0.f, 0.f, 0.f, 0.f};
  for (int d = 0; d < deg; ++d) {
    const uint4v u = out_chb4[(size_t)(off + d) * 2 + half];
#pragma unroll
    for (int p = 0; p < 4; ++p) {
      a[2 * p]     += bflo2f(u[p]);
      a[2 * p + 1] += bfhi2f(u[p]);
    }
  }
  const float inv = 1.0f / fmaxf((float)deg, 1.0f);
  float4v r0, r1;
#pragma unroll
  for (int p = 0; p < 4; ++p) { r0[p] = a[p] * inv; r1[p] = a[4 + p] * inv; }
  float* dst = out + (size_t)gid * 16 + 8 * half;
  *(float4v*)dst       = r0;
  *(float4v*)(dst + 4) = r1;
}

// fallback divide
__global__ void nf_final(float* __restrict__ out, const int* __restrict__ counts, int n) {
  int i = blockIdx.x * blockDim.x + threadIdx.x;
  if (i < n) {
    float c = (float)counts[i >> 4];
    out[i] = out[i] / fmaxf(c, 1.0f);
  }
}

extern "C" void kernel_launch(void* const* d_in, const int* in_sizes, int n_in,
                              void* d_out, int out_size, void* d_ws, size_t ws_size,
                              hipStream_t stream) {
  const int*   in_edges  = (const int*)d_in[0];
  const int*   out_edges = (const int*)d_in[1];
  const float* ef        = (const float*)d_in[2];
  const float* coords    = (const float*)d_in[3];
  const float* W1  = (const float*)d_in[4];
  const float* b1  = (const float*)d_in[5];
  const float* g1  = (const float*)d_in[6];
  const float* be1 = (const float*)d_in[7];
  const float* W2  = (const float*)d_in[8];
  const float* b2  = (const float*)d_in[9];
  const float* g2  = (const float*)d_in[10];
  const float* be2 = (const float*)d_in[11];
  const float* W3  = (const float*)d_in[12];
  const float* b3  = (const float*)d_in[13];

  const int E = in_sizes[0];
  const int N = in_sizes[2] / 16;
  const int ntiles = (E + 31) / 32;
  float* out = (float*)d_out;

  // ws: out_chb [8E u32 bf16x2] | counts [N] | total [1] | offsets [N] | cursor [N]
  const size_t need = ((size_t)E * 8 + 3 * (size_t)N + 1) * 4;

  if (ws_size >= need) {
    unsigned* out_chb = (unsigned*)d_ws;
    int*      counts  = (int*)(out_chb + (size_t)E * 8);
    int*      total   = counts + N;
    int*      offsets = total + 1;
    int*      cursor  = offsets + N;

    (void)hipMemsetAsync(counts, 0, ((size_t)N + 1) * sizeof(int), stream);
    nf_hist<<<(E / 4 + 255) / 256 + 1, 256, 0, stream>>>(out_edges, counts, E);
    nf_alloc<<<(N + 255) / 256, 256, 0, stream>>>(counts, offsets, cursor, total, N);
    nf_main<0><<<1024, 256, 0, stream>>>(in_edges, out_edges, ef, coords,
                                         W1, b1, g1, be1, W2, b2, g2, be2, W3, b3,
                                         out_chb, nullptr, cursor, E, ntiles);
    nf_reduce<<<(N + 127) / 128, 256, 0, stream>>>((const uint4v*)out_chb, counts,
                                                   offsets, out, N);
  } else {
    // fallback: direct f32 atomics
    int* counts = (int*)d_ws;
    (void)hipMemsetAsync(out, 0, (size_t)out_size * sizeof(float), stream);
    (void)hipMemsetAsync(counts, 0, (size_t)N * sizeof(int), stream);
    nf_main<1><<<1024, 256, 0, stream>>>(in_edges, out_edges, ef, coords,
                                         W1, b1, g1, be1, W2, b2, g2, be2, W3, b3,
                                         out, counts, nullptr, E, ntiles);
    nf_final<<<(out_size + 255) / 256, 256, 0, stream>>>(out, counts, out_size);
  }
}

// Round 19
// 187.250 us; speedup vs baseline: 2.8486x; 2.8486x over previous
//
#include <hip/hip_runtime.h>
#include <hip/hip_bf16.h>

// NeuralFieldCosmo — R19: R18 (32x32x8 formulation, numerics VERIFIED,
// absmax 0.046875) + ONE change: #pragma unroll 1 on the epilogue mt-loop.
// R18 spilled ~21 regs/iter (FETCH 57->717MB) — the fully-unrolled 8-iter
// mt loop let the scheduler hoist ~190 regs of LDS loads (exact R3 failure
// mode; R3's unroll-bound fix cut 4.4GB->0.78GB). Body keeps 2 independent
// per-o chains; 4-wave TLP covers the rest.
// Ledger: raw cvt_pk asm banned (R8/R9/R10 NaN). f2bf + packc verified.
// 32x32x8 A/B k-map (row=lane&31, k=4*(lane>>5)+j) VERIFIED by R18 pass.
// C/D: col=lane&31, row=(r&3)+8(r>>2)+4(lane>>5). Spill tell = FETCH>150MB
// -> revert to R17 (211us) as final.

typedef __attribute__((ext_vector_type(4)))  short    short4v;  // 4 bf16 (2 VGPR)
typedef __attribute__((ext_vector_type(4)))  float    float4v;
typedef __attribute__((ext_vector_type(16))) float    f32x16;
typedef __attribute__((ext_vector_type(4)))  unsigned uint4v;
typedef __attribute__((ext_vector_type(2)))  unsigned uint2v;

constexpr float LN_EPS   = 1e-5f;
constexpr float LOG2E_X2 = 2.8853900817779268f;  // 2*log2(e)

// RNE float -> bf16 bits (staging; verified R4-R18)
__device__ __forceinline__ unsigned f2bf(float x) {
  unsigned u = __builtin_bit_cast(unsigned, x);
  u += 0x7FFFu + ((u >> 16) & 1u);
  return u >> 16;
}
__device__ __forceinline__ unsigned pack2(float lo, float hi) {
  return f2bf(lo) | (f2bf(hi) << 16);
}
// HOT pack: library bf16x2 cvt (RNE), low 16 bits = lo. Verified R16-R18.
__device__ __forceinline__ unsigned packc(float lo, float hi) {
  float2 v; v.x = lo; v.y = hi;
  const __hip_bfloat162 b = __float22bfloat162_rn(v);
  static_assert(sizeof(__hip_bfloat162) == 4, "bf16x2 must be 4 bytes");
  unsigned r;
  __builtin_memcpy(&r, &b, 4);
  return r;
}
__device__ __forceinline__ float bflo2f(unsigned u) {
  return __builtin_bit_cast(float, u << 16);
}
__device__ __forceinline__ float bfhi2f(unsigned u) {
  return __builtin_bit_cast(float, u & 0xFFFF0000u);
}
// rcp(exp2(x)+1)
__device__ __forceinline__ float sigm2(float x) {
  return __builtin_amdgcn_rcpf(__builtin_amdgcn_exp2f(x) + 1.0f);
}

__device__ __forceinline__ f32x16 mfma32(short4v a, short4v b, f32x16 c) {
#if __has_builtin(__builtin_amdgcn_mfma_f32_32x32x8bf16_1k)
  return __builtin_amdgcn_mfma_f32_32x32x8bf16_1k(a, b, c, 0, 0, 0);
#else
  asm volatile("v_mfma_f32_32x32x8_bf16 %0, %1, %2, %0\n\ts_nop 7\n\ts_nop 7"
               : "+v"(c) : "v"(a), "v"(b));
  return c;
#endif
}

// LN over 32 chs (16/lane; partner lane^32 holds complement), affine (packed
// bf16 pairs), relu, pack to 4 B-frag K-segments. hv idx s*4+j <-> ch 8s+4h+j.
__device__ __forceinline__ void ln_relu_pack32(const float* hv, const unsigned* gp,
                                               const unsigned* bp, short4v* bh) {
  float sum = 0.f, ss = 0.f;
#pragma unroll
  for (int i = 0; i < 16; ++i) { sum += hv[i]; ss += hv[i] * hv[i]; }
  sum += __shfl_xor(sum, 32);
  ss  += __shfl_xor(ss, 32);
  const float m   = sum * (1.0f / 32.0f);
  const float var = fmaxf(ss * (1.0f / 32.0f) - m * m, 0.f);
  const float rs  = rsqrtf(var + LN_EPS);
#pragma unroll
  for (int s = 0; s < 4; ++s) {
    float y[4];
#pragma unroll
    for (int p = 0; p < 2; ++p) {
      const unsigned g = gp[s * 2 + p], b = bp[s * 2 + p];
      y[2 * p]     = fmaxf((hv[s * 4 + 2 * p]     - m) * rs * bflo2f(g) + bflo2f(b), 0.f);
      y[2 * p + 1] = fmaxf((hv[s * 4 + 2 * p + 1] - m) * rs * bfhi2f(g) + bfhi2f(b), 0.f);
    }
    uint2v u; u[0] = packc(y[0], y[1]); u[1] = packc(y[2], y[3]);
    bh[s] = __builtin_bit_cast(short4v, u);
  }
}

// ---------------- CSR build (R17-verified) ----------------

__global__ void nf_hist(const int* __restrict__ out_edges, int* __restrict__ counts, int E) {
  const int t4 = (blockIdx.x * blockDim.x + threadIdx.x) * 4;
  if (t4 + 3 < E) {
    const int4 v = *(const int4*)(out_edges + t4);
    atomicAdd(&counts[v.x], 1);
    atomicAdd(&counts[v.y], 1);
    atomicAdd(&counts[v.z], 1);
    atomicAdd(&counts[v.w], 1);
  } else {
    for (int i = t4; i < E; ++i) atomicAdd(&counts[out_edges[i]], 1);
  }
}

__global__ void nf_alloc(const int* __restrict__ counts, int* __restrict__ offsets,
                         int* __restrict__ cursor, int* __restrict__ total, int N) {
  const int i = blockIdx.x * blockDim.x + threadIdx.x;
  const int lane = threadIdx.x & 63;
  int c = (i < N) ? counts[i] : 0;
  int sc = c;
#pragma unroll
  for (int d = 1; d < 64; d <<= 1) {
    int v = __shfl_up(sc, d);
    if (lane >= d) sc += v;
  }
  const int excl = sc - c;
  const int wtot = __shfl(sc, 63);
  int base = 0;
  if (lane == 0) base = atomicAdd(total, wtot);
  base = __shfl(base, 0);
  if (i < N) {
    offsets[i] = base + excl;
    cursor[i]  = base + excl;
  }
}

// ---------------- main compute ----------------
// SCATTER_MODE: 0 = CSR-ordered bf16 stream, 1 = direct f32 atomics fallback

template <int SCATTER_MODE>
__global__ __launch_bounds__(256, 2)
void nf_main(const int* __restrict__ in_edges,
             const int* __restrict__ out_edges,
             const float* __restrict__ ef,
             const float* __restrict__ coords,
             const float* __restrict__ W1, const float* __restrict__ b1,
             const float* __restrict__ g1, const float* __restrict__ be1,
             const float* __restrict__ W2, const float* __restrict__ b2,
             const float* __restrict__ g2, const float* __restrict__ be2,
             const float* __restrict__ W3, const float* __restrict__ b3,
             void* __restrict__ out_ch,   // mode0: unsigned[E][8] bf16x2 ; mode1: float sums (d_out)
             int* __restrict__ aux,       // mode1: counts
             int* __restrict__ cursor,    // mode0: [N]
             int E, int ntiles)
{
  // W3 A-frags (prescaled 2log2e): [mt][blk][lane][4 u32]  (16 KB)
  __shared__ __align__(16) unsigned sA3[8 * 2 * 64 * 4];
  __shared__ __align__(16) float    sB3f[256];     // 2log2e*b3, [o][i]
  // per-h packed consts: [0..23] w1 (d*8+sp), [24..31] b1,
  // [32..39] g1, [40..47] be1, [48..55] g2, [56..63] be2
  __shared__ __align__(16) unsigned sK[2][64];
  __shared__ __align__(16) float    sB2f[2][16];   // b2 in C-row order

  const int t    = threadIdx.x;
  const int l    = t & 63;
  const int h    = l >> 5;     // half: k-group / C-row group
  const int ecol = l & 31;     // edge column within 32-edge tile

  // ---- one-time LDS staging (R18-verified) ----
#pragma unroll
  for (int rep = 0; rep < 16; ++rep) {
    const int idx = rep * 256 + t;
    const int u = idx & 3, ll = (idx >> 2) & 63, b = (idx >> 8) & 1, mt = idx >> 9;
    const int s = b * 2 + (u >> 1), jp = u & 1;
    const int hh = ll >> 5, m = ll & 31;
    const int o = 2 * mt + (m >> 4), i = m & 15;
    const int k0 = 8 * s + 4 * hh + 2 * jp;
    sA3[idx] = pack2(LOG2E_X2 * W3[(size_t)k0 * 256 + o * 16 + i],
                     LOG2E_X2 * W3[(size_t)(k0 + 1) * 256 + o * 16 + i]);
  }
  sB3f[t] = LOG2E_X2 * b3[t];
  if (t < 128) {
    const int hh = t >> 6, i = t & 63;
    const int sp = i & 7;
    const int ch = 8 * (sp >> 1) + 4 * hh + 2 * (sp & 1);
    if (i < 24) {
      const int d = i >> 3;
      sK[hh][i] = pack2(W1[d * 32 + ch], W1[d * 32 + ch + 1]);
    } else {
      const float* src = (i < 32) ? b1 : (i < 40) ? g1 : (i < 48) ? be1
                        : (i < 56) ? g2 : be2;
      sK[hh][i] = pack2(src[ch], src[ch + 1]);
    }
  }
  if (t < 32) {
    const int hh = t >> 4, r = t & 15;
    sB2f[hh][r] = b2[(r & 3) + 8 * (r >> 2) + 4 * hh];
  }

  // L2 A-frags in regs (8 VGPR): A[m=ch_out=ecol][k=8s+4h+j] = W2[k][ecol]
  short4v a2[4];
#pragma unroll
  for (int s = 0; s < 4; ++s) {
    short4v v;
#pragma unroll
    for (int j = 0; j < 4; ++j)
      v[j] = (short)f2bf(W2[(8 * s + 4 * h + j) * 32 + ecol]);
    a2[s] = v;
  }
  __syncthreads();

  const int gwave  = (blockIdx.x * blockDim.x + t) >> 6;
  const int nwaves = (gridDim.x * blockDim.x) >> 6;

  // ---- prologue: tile-0 state ----
  int tile = gwave;
  bool valid = false; int oe = 0;
  float x0 = 0.f, x1 = 0.f, x2 = 0.f;
  float4v f4a = {}, f4b = {};
  if (tile < ntiles) {
    const int eIdx = tile * 32 + ecol;
    valid = eIdx < E;
    const int eS = valid ? eIdx : 0;
    const int ie = in_edges[eS]; oe = out_edges[eS];
    x0 = coords[3 * eS]; x1 = coords[3 * eS + 1]; x2 = coords[3 * eS + 2];
    f4a = *(const float4v*)(ef + (size_t)ie * 16 + 4 * h);
    f4b = *(const float4v*)(ef + (size_t)ie * 16 + 8 + 4 * h);
  }

  for (; tile < ntiles; tile += nwaves) {
    // ---- prefetch next tile indices + coords ----
    const int tn = tile + nwaves;
    int ieN = 0, oeN = 0; bool validN = false;
    float x0N = 0.f, x1N = 0.f, x2N = 0.f;
    if (tn < ntiles) {
      const int eIdxN = tn * 32 + ecol;
      validN = eIdxN < E;
      const int eSN = validN ? eIdxN : 0;
      ieN = in_edges[eSN]; oeN = out_edges[eSN];
      x0N = coords[3 * eSN]; x1N = coords[3 * eSN + 1]; x2N = coords[3 * eSN + 2];
    }

    // CSR slot (atomic latency hides under MLP)
    int pos = 0;
    if (SCATTER_MODE == 0 && h == 0 && valid)
      pos = atomicAdd(&cursor[oe], 1);

    // ---- L1: 3 -> 32 (16 chs/lane; consts via h-broadcast LDS) ----
    float hv[16];
    {
      const uint4v* kk = (const uint4v*)&sK[h][0];
      const uint4v b1a = kk[6], b1b = kk[7];
#pragma unroll
      for (int sp = 0; sp < 8; ++sp) {
        const unsigned ub = (sp < 4) ? b1a[sp] : b1b[sp - 4];
        const int base = (sp >> 1) * 4 + (sp & 1) * 2;
        hv[base]     = bflo2f(ub);
        hv[base + 1] = bfhi2f(ub);
      }
#pragma unroll
      for (int d = 0; d < 3; ++d) {
        const uint4v wa = kk[d * 2], wb = kk[d * 2 + 1];
        const float xd = (d == 0) ? x0 : (d == 1) ? x1 : x2;
#pragma unroll
        for (int sp = 0; sp < 8; ++sp) {
          const unsigned uw = (sp < 4) ? wa[sp] : wb[sp - 4];
          const int base = (sp >> 1) * 4 + (sp & 1) * 2;
          hv[base]     = fmaf(xd, bflo2f(uw), hv[base]);
          hv[base + 1] = fmaf(xd, bfhi2f(uw), hv[base + 1]);
        }
      }
    }
    short4v bh[4];
    {
      unsigned lnc[16];
      const uint4v* kg = (const uint4v*)&sK[h][32];
#pragma unroll
      for (int r4 = 0; r4 < 4; ++r4) {
        const uint4v v = kg[r4];
        lnc[r4 * 4 + 0] = v[0]; lnc[r4 * 4 + 1] = v[1];
        lnc[r4 * 4 + 2] = v[2]; lnc[r4 * 4 + 3] = v[3];
      }
      ln_relu_pack32(hv, &lnc[0], &lnc[8], bh);
    }

    // ---- L2 GEMM: 32 -> 32 (one 32x32 tile, K=32 via 4 segments) ----
    f32x16 c;
    {
      const float4v* bb = (const float4v*)&sB2f[h][0];
      const float4v c0 = bb[0], c1 = bb[1], c2 = bb[2], c3i = bb[3];
#pragma unroll
      for (int e = 0; e < 4; ++e) {
        c[e] = c0[e]; c[4 + e] = c1[e]; c[8 + e] = c2[e]; c[12 + e] = c3i[e];
      }
    }
#pragma unroll
    for (int s = 0; s < 4; ++s) c = mfma32(a2[s], bh[s], c);

    {
      float hv2[16];
#pragma unroll
      for (int r = 0; r < 16; ++r) hv2[r] = c[r];
      unsigned ln2[16];
      const uint4v* kg2 = (const uint4v*)&sK[h][48];
#pragma unroll
      for (int r4 = 0; r4 < 4; ++r4) {
        const uint4v v = kg2[r4];
        ln2[r4 * 4 + 0] = v[0]; ln2[r4 * 4 + 1] = v[1];
        ln2[r4 * 4 + 2] = v[2]; ln2[r4 * 4 + 3] = v[3];
      }
      ln_relu_pack32(hv2, &ln2[0], &ln2[8], bh);
    }

    // ---- prefetch next tile's feature gather (ieN landed) ----
    float4v f4aN = {}, f4bN = {};
    if (tn < ntiles) {
      f4aN = *(const float4v*)(ef + (size_t)ieN * 16 + 4 * h);
      f4bN = *(const float4v*)(ef + (size_t)ieN * 16 + 8 + 4 * h);
    }

    // lane-half partial of sum_i f[i] (completed by the pr shfl_xor(32))
    const float sumf = (f4a[0] + f4a[1]) + (f4a[2] + f4a[3])
                     + (f4b[0] + f4b[1]) + (f4b[2] + f4b[3]);

    // ---- L3: 8 m-tiles (2 o's each), K=32; tanh-algebra epilogue ----
    // unroll 1: R18's full unroll hoisted ~190 regs of LDS loads -> 21-reg
    // spill/iter (R3 failure mode). Rolled loop bounds the live set.
#pragma unroll 1
    for (int mt = 0; mt < 8; ++mt) {
      const uint4v av0 = *(const uint4v*)&sA3[mt * 512 + (l << 2)];
      const uint4v av1 = *(const uint4v*)&sA3[mt * 512 + 256 + (l << 2)];
      f32x16 c3;
      {
        const float4v i0 = *(const float4v*)&sB3f[(2 * mt) * 16 + 4 * h];
        const float4v i1 = *(const float4v*)&sB3f[(2 * mt) * 16 + 8 + 4 * h];
        const float4v i2 = *(const float4v*)&sB3f[(2 * mt + 1) * 16 + 4 * h];
        const float4v i3 = *(const float4v*)&sB3f[(2 * mt + 1) * 16 + 8 + 4 * h];
#pragma unroll
        for (int e = 0; e < 4; ++e) {
          c3[e] = i0[e]; c3[4 + e] = i1[e]; c3[8 + e] = i2[e]; c3[12 + e] = i3[e];
        }
      }
      uint2v u01, u23;
      u01[0] = av0[0]; u01[1] = av0[1];  u23[0] = av0[2]; u23[1] = av0[3];
      c3 = mfma32(__builtin_bit_cast(short4v, u01), bh[0], c3);
      c3 = mfma32(__builtin_bit_cast(short4v, u23), bh[1], c3);
      u01[0] = av1[0]; u01[1] = av1[1];  u23[0] = av1[2]; u23[1] = av1[3];
      c3 = mfma32(__builtin_bit_cast(short4v, u01), bh[2], c3);
      c3 = mfma32(__builtin_bit_cast(short4v, u23), bh[3], c3);

      float dot0 = 0.f, dot1 = 0.f;
#pragma unroll
      for (int j = 0; j < 4; ++j) {
        dot0 = fmaf(f4a[j], sigm2(c3[j]),      dot0);
        dot0 = fmaf(f4b[j], sigm2(c3[4 + j]),  dot0);
        dot1 = fmaf(f4a[j], sigm2(c3[8 + j]),  dot1);
        dot1 = fmaf(f4b[j], sigm2(c3[12 + j]), dot1);
      }
      float pr0 = fmaf(-2.0f, dot0, sumf);
      float pr1 = fmaf(-2.0f, dot1, sumf);
      pr0 += __shfl_xor(pr0, 32);
      pr1 += __shfl_xor(pr1, 32);

      if (SCATTER_MODE == 0) {
        if (h == 0 && valid)
          ((unsigned*)out_ch)[(size_t)pos * 8 + mt] = packc(pr0, pr1);
      } else {
        if (h == 0 && valid) {
          float* sums = (float*)out_ch;
          atomicAdd(&sums[(size_t)oe * 16 + 2 * mt],     pr0);
          atomicAdd(&sums[(size_t)oe * 16 + 2 * mt + 1], pr1);
        }
      }
    }
    if (SCATTER_MODE == 1) {
      if (h == 0 && valid) atomicAdd(&aux[oe], 1);
    }

    // rotate pipeline state
    valid = validN; oe = oeN;
    x0 = x0N; x1 = x1N; x2 = x2N; f4a = f4aN; f4b = f4bN;
  }
}

// ---------------- per-node reduce (CSR path, bf16 rows; R17-verified) ----------------

__global__ __launch_bounds__(256)
void nf_reduce(const uint4v* __restrict__ out_chb4, const int* __restrict__ counts,
               const int* __restrict__ offsets, float* __restrict__ out, int N) {
  const int gid  = blockIdx.x * 128 + (threadIdx.x >> 1);  // node
  const int half = threadIdx.x & 1;                        // channels 8h..8h+7
  if (gid >= N) return;
  const int deg = counts[gid];
  const int off = offsets[gid];
  float a[8] = {0.f, 0.f, 0.f, 0.f, 0.f, 0.f, 0.f, 0.f};
  for (int d = 0; d < deg; ++d) {
    const uint4v u = out_chb4[(size_t)(off + d) * 2 + half];
#pragma unroll
    for (int p = 0; p < 4; ++p) {
      a[2 * p]     += bflo2f(u[p]);
      a[2 * p + 1] += bfhi2f(u[p]);
    }
  }
  const float inv = 1.0f / fmaxf((float)deg, 1.0f);
  float4v r0, r1;
#pragma unroll
  for (int p = 0; p < 4; ++p) { r0[p] = a[p] * inv; r1[p] = a[4 + p] * inv; }
  float* dst = out + (size_t)gid * 16 + 8 * half;
  *(float4v*)dst       = r0;
  *(float4v*)(dst + 4) = r1;
}

// fallback divide
__global__ void nf_final(float* __restrict__ out, const int* __restrict__ counts, int n) {
  int i = blockIdx.x * blockDim.x + threadIdx.x;
  if (i < n) {
    float c = (float)counts[i >> 4];
    out[i] = out[i] / fmaxf(c, 1.0f);
  }
}

extern "C" void kernel_launch(void* const* d_in, const int* in_sizes, int n_in,
                              void* d_out, int out_size, void* d_ws, size_t ws_size,
                              hipStream_t stream) {
  const int*   in_edges  = (const int*)d_in[0];
  const int*   out_edges = (const int*)d_in[1];
  const float* ef        = (const float*)d_in[2];
  const float* coords    = (const float*)d_in[3];
  const float* W1  = (const float*)d_in[4];
  const float* b1  = (const float*)d_in[5];
  const float* g1  = (const float*)d_in[6];
  const float* be1 = (const float*)d_in[7];
  const float* W2  = (const float*)d_in[8];
  const float* b2  = (const float*)d_in[9];
  const float* g2  = (const float*)d_in[10];
  const float* be2 = (const float*)d_in[11];
  const float* W3  = (const float*)d_in[12];
  const float* b3  = (const float*)d_in[13];

  const int E = in_sizes[0];
  const int N = in_sizes[2] / 16;
  const int ntiles = (E + 31) / 32;
  float* out = (float*)d_out;

  // ws: out_chb [8E u32 bf16x2] | counts [N] | total [1] | offsets [N] | cursor [N]
  const size_t need = ((size_t)E * 8 + 3 * (size_t)N + 1) * 4;

  if (ws_size >= need) {
    unsigned* out_chb = (unsigned*)d_ws;
    int*      counts  = (int*)(out_chb + (size_t)E * 8);
    int*      total   = counts + N;
    int*      offsets = total + 1;
    int*      cursor  = offsets + N;

    (void)hipMemsetAsync(counts, 0, ((size_t)N + 1) * sizeof(int), stream);
    nf_hist<<<(E / 4 + 255) / 256 + 1, 256, 0, stream>>>(out_edges, counts, E);
    nf_alloc<<<(N + 255) / 256, 256, 0, stream>>>(counts, offsets, cursor, total, N);
    nf_main<0><<<1024, 256, 0, stream>>>(in_edges, out_edges, ef, coords,
                                         W1, b1, g1, be1, W2, b2, g2, be2, W3, b3,
                                         out_chb, nullptr, cursor, E, ntiles);
    nf_reduce<<<(N + 127) / 128, 256, 0, stream>>>((const uint4v*)out_chb, counts,
                                                   offsets, out, N);
  } else {
    // fallback: direct f32 atomics
    int* counts = (int*)d_ws;
    (void)hipMemsetAsync(out, 0, (size_t)out_size * sizeof(float), stream);
    (void)hipMemsetAsync(counts, 0, (size_t)N * sizeof(int), stream);
    nf_main<1><<<1024, 256, 0, stream>>>(in_edges, out_edges, ef, coords,
                                         W1, b1, g1, be1, W2, b2, g2, be2, W3, b3,
                                         out, counts, nullptr, E, ntiles);
    nf_final<<<(out_size + 255) / 256, 256, 0, stream>>>(out, counts, out_size);
  }
}

// Round 20
// 179.527 us; speedup vs baseline: 2.9712x; 1.0430x over previous
//
#include <hip/hip_runtime.h>
#include <hip/hip_bf16.h>

// NeuralFieldCosmo — R20: R19 base (verified 187us, absmax 0.046875) + two
// pure VALU deletions using only hardware-verified machinery:
// (1) L1 (3->32) as ONE mfma32: coords packed to the B-frag (k-map verified
//     R18/R19), W1 as 1-reg A-frag, C-init = b1 f32 from LDS. Deletes ~90
//     VALU + collapses L1's serial chain. Coords now bf16-rounded (~0.2%).
// (2) LN affine consts (g/be) stored f32 in LDS (broadcast b128 reads)
//     instead of packed-bf16 unpacking: -64 VALU/tile, +8 DS reads.
// Epilogue (unroll 1 — R19's spill fix), plumbing, CSR all R19-verbatim.
// Ledger: raw cvt_pk asm banned. f2bf + packc verified. 32x32x8 A/B/C
// layouts verified R18/R19. Spill tell = FETCH > 150 MB.
// Kill-rule: absmax > 0.12 -> revert L1-MFMA (coords rounding too hot).

typedef __attribute__((ext_vector_type(4)))  short    short4v;  // 4 bf16 (2 VGPR)
typedef __attribute__((ext_vector_type(4)))  float    float4v;
typedef __attribute__((ext_vector_type(16))) float    f32x16;
typedef __attribute__((ext_vector_type(4)))  unsigned uint4v;
typedef __attribute__((ext_vector_type(2)))  unsigned uint2v;

constexpr float LN_EPS   = 1e-5f;
constexpr float LOG2E_X2 = 2.8853900817779268f;  // 2*log2(e)

// RNE float -> bf16 bits (staging; verified R4-R19)
__device__ __forceinline__ unsigned f2bf(float x) {
  unsigned u = __builtin_bit_cast(unsigned, x);
  u += 0x7FFFu + ((u >> 16) & 1u);
  return u >> 16;
}
__device__ __forceinline__ unsigned pack2(float lo, float hi) {
  return f2bf(lo) | (f2bf(hi) << 16);
}
// HOT pack: library bf16x2 cvt (RNE), low 16 bits = lo. Verified R16-R19.
__device__ __forceinline__ unsigned packc(float lo, float hi) {
  float2 v; v.x = lo; v.y = hi;
  const __hip_bfloat162 b = __float22bfloat162_rn(v);
  static_assert(sizeof(__hip_bfloat162) == 4, "bf16x2 must be 4 bytes");
  unsigned r;
  __builtin_memcpy(&r, &b, 4);
  return r;
}
__device__ __forceinline__ float bflo2f(unsigned u) {
  return __builtin_bit_cast(float, u << 16);
}
__device__ __forceinline__ float bfhi2f(unsigned u) {
  return __builtin_bit_cast(float, u & 0xFFFF0000u);
}
// rcp(exp2(x)+1)
__device__ __forceinline__ float sigm2(float x) {
  return __builtin_amdgcn_rcpf(__builtin_amdgcn_exp2f(x) + 1.0f);
}

__device__ __forceinline__ f32x16 mfma32(short4v a, short4v b, f32x16 c) {
#if __has_builtin(__builtin_amdgcn_mfma_f32_32x32x8bf16_1k)
  return __builtin_amdgcn_mfma_f32_32x32x8bf16_1k(a, b, c, 0, 0, 0);
#else
  asm volatile("v_mfma_f32_32x32x8_bf16 %0, %1, %2, %0\n\ts_nop 7\n\ts_nop 7"
               : "+v"(c) : "v"(a), "v"(b));
  return c;
#endif
}

// LN over 32 chs (16/lane; lane^32 holds complement), affine from f32 LDS
// (broadcast reads), relu, pack to 4 B-frag K-segments via packc.
__device__ __forceinline__ void ln_relu_pack32f(const float* hv,
                                                const float* __restrict__ gf,
                                                const float* __restrict__ bef,
                                                short4v* bh) {
  float sum = 0.f, ss = 0.f;
#pragma unroll
  for (int i = 0; i < 16; ++i) { sum += hv[i]; ss += hv[i] * hv[i]; }
  sum += __shfl_xor(sum, 32);
  ss  += __shfl_xor(ss, 32);
  const float m   = sum * (1.0f / 32.0f);
  const float var = fmaxf(ss * (1.0f / 32.0f) - m * m, 0.f);
  const float rs  = rsqrtf(var + LN_EPS);
#pragma unroll
  for (int s = 0; s < 4; ++s) {
    const float4v gv = *(const float4v*)&gf[s * 4];
    const float4v bv = *(const float4v*)&bef[s * 4];
    float y[4];
#pragma unroll
    for (int j = 0; j < 4; ++j)
      y[j] = fmaxf((hv[s * 4 + j] - m) * rs * gv[j] + bv[j], 0.f);
    uint2v u; u[0] = packc(y[0], y[1]); u[1] = packc(y[2], y[3]);
    bh[s] = __builtin_bit_cast(short4v, u);
  }
}

// ---------------- CSR build (R17-verified) ----------------

__global__ void nf_hist(const int* __restrict__ out_edges, int* __restrict__ counts, int E) {
  const int t4 = (blockIdx.x * blockDim.x + threadIdx.x) * 4;
  if (t4 + 3 < E) {
    const int4 v = *(const int4*)(out_edges + t4);
    atomicAdd(&counts[v.x], 1);
    atomicAdd(&counts[v.y], 1);
    atomicAdd(&counts[v.z], 1);
    atomicAdd(&counts[v.w], 1);
  } else {
    for (int i = t4; i < E; ++i) atomicAdd(&counts[out_edges[i]], 1);
  }
}

__global__ void nf_alloc(const int* __restrict__ counts, int* __restrict__ offsets,
                         int* __restrict__ cursor, int* __restrict__ total, int N) {
  const int i = blockIdx.x * blockDim.x + threadIdx.x;
  const int lane = threadIdx.x & 63;
  int c = (i < N) ? counts[i] : 0;
  int sc = c;
#pragma unroll
  for (int d = 1; d < 64; d <<= 1) {
    int v = __shfl_up(sc, d);
    if (lane >= d) sc += v;
  }
  const int excl = sc - c;
  const int wtot = __shfl(sc, 63);
  int base = 0;
  if (lane == 0) base = atomicAdd(total, wtot);
  base = __shfl(base, 0);
  if (i < N) {
    offsets[i] = base + excl;
    cursor[i]  = base + excl;
  }
}

// ---------------- main compute ----------------
// SCATTER_MODE: 0 = CSR-ordered bf16 stream, 1 = direct f32 atomics fallback

template <int SCATTER_MODE>
__global__ __launch_bounds__(256, 2)
void nf_main(const int* __restrict__ in_edges,
             const int* __restrict__ out_edges,
             const float* __restrict__ ef,
             const float* __restrict__ coords,
             const float* __restrict__ W1, const float* __restrict__ b1,
             const float* __restrict__ g1, const float* __restrict__ be1,
             const float* __restrict__ W2, const float* __restrict__ b2,
             const float* __restrict__ g2, const float* __restrict__ be2,
             const float* __restrict__ W3, const float* __restrict__ b3,
             void* __restrict__ out_ch,   // mode0: unsigned[E][8] bf16x2 ; mode1: float sums (d_out)
             int* __restrict__ aux,       // mode1: counts
             int* __restrict__ cursor,    // mode0: [N]
             int E, int ntiles)
{
  // W3 A-frags (prescaled 2log2e): [mt][blk][lane][4 u32]  (16 KB)
  __shared__ __align__(16) unsigned sA3[8 * 2 * 64 * 4];
  __shared__ __align__(16) float    sB3f[256];     // 2log2e*b3, [o][i]
  __shared__ __align__(16) float    sB2f[2][16];   // b2 in C-row order
  // f32 per-h lane-channel consts, hv order (idx s*4+j <-> ch 8s+4h+j)
  __shared__ __align__(16) float    sB1f[2][16];
  __shared__ __align__(16) float    sG1[2][16],  sBe1[2][16];
  __shared__ __align__(16) float    sG2[2][16],  sBe2[2][16];

  const int t    = threadIdx.x;
  const int l    = t & 63;
  const int h    = l >> 5;     // half: k-group / C-row group
  const int ecol = l & 31;     // edge column within 32-edge tile

  // ---- one-time LDS staging (sA3/sB3f R18-verified) ----
#pragma unroll
  for (int rep = 0; rep < 16; ++rep) {
    const int idx = rep * 256 + t;
    const int u = idx & 3, ll = (idx >> 2) & 63, b = (idx >> 8) & 1, mt = idx >> 9;
    const int s = b * 2 + (u >> 1), jp = u & 1;
    const int hh = ll >> 5, m = ll & 31;
    const int o = 2 * mt + (m >> 4), i = m & 15;
    const int k0 = 8 * s + 4 * hh + 2 * jp;
    sA3[idx] = pack2(LOG2E_X2 * W3[(size_t)k0 * 256 + o * 16 + i],
                     LOG2E_X2 * W3[(size_t)(k0 + 1) * 256 + o * 16 + i]);
  }
  sB3f[t] = LOG2E_X2 * b3[t];
  if (t < 32) {
    const int hh = t >> 4, r = t & 15;          // r = s*4+j
    const int ch = 8 * (r >> 2) + 4 * hh + (r & 3);
    sB2f[hh][r] = b2[ch];
    sB1f[hh][r] = b1[ch];
    sG1[hh][r]  = g1[ch];   sBe1[hh][r] = be1[ch];
    sG2[hh][r]  = g2[ch];   sBe2[hh][r] = be2[ch];
  }

  // L1 A-frag (1 reg-pair): A[m=ch_out=ecol][k=4h+j] = W1[k][ecol], k<3
  short4v a1;
#pragma unroll
  for (int j = 0; j < 4; ++j) {
    const int k = 4 * h + j;
    a1[j] = (k < 3) ? (short)f2bf(W1[k * 32 + ecol]) : (short)0;
  }
  // L2 A-frags (8 VGPR): A[m=ecol][k=8s+4h+j] = W2[k][ecol]
  short4v a2[4];
#pragma unroll
  for (int s = 0; s < 4; ++s) {
    short4v v;
#pragma unroll
    for (int j = 0; j < 4; ++j)
      v[j] = (short)f2bf(W2[(8 * s + 4 * h + j) * 32 + ecol]);
    a2[s] = v;
  }
  __syncthreads();

  const int gwave  = (blockIdx.x * blockDim.x + t) >> 6;
  const int nwaves = (gridDim.x * blockDim.x) >> 6;

  // ---- prologue: tile-0 state ----
  int tile = gwave;
  bool valid = false; int oe = 0;
  float x0 = 0.f, x1 = 0.f, x2 = 0.f;
  float4v f4a = {}, f4b = {};
  if (tile < ntiles) {
    const int eIdx = tile * 32 + ecol;
    valid = eIdx < E;
    const int eS = valid ? eIdx : 0;
    const int ie = in_edges[eS]; oe = out_edges[eS];
    x0 = coords[3 * eS]; x1 = coords[3 * eS + 1]; x2 = coords[3 * eS + 2];
    f4a = *(const float4v*)(ef + (size_t)ie * 16 + 4 * h);
    f4b = *(const float4v*)(ef + (size_t)ie * 16 + 8 + 4 * h);
  }

  for (; tile < ntiles; tile += nwaves) {
    // ---- prefetch next tile indices + coords ----
    const int tn = tile + nwaves;
    int ieN = 0, oeN = 0; bool validN = false;
    float x0N = 0.f, x1N = 0.f, x2N = 0.f;
    if (tn < ntiles) {
      const int eIdxN = tn * 32 + ecol;
      validN = eIdxN < E;
      const int eSN = validN ? eIdxN : 0;
      ieN = in_edges[eSN]; oeN = out_edges[eSN];
      x0N = coords[3 * eSN]; x1N = coords[3 * eSN + 1]; x2N = coords[3 * eSN + 2];
    }

    // CSR slot (atomic latency hides under MLP)
    int pos = 0;
    if (SCATTER_MODE == 0 && h == 0 && valid)
      pos = atomicAdd(&cursor[oe], 1);

    // ---- L1 as one MFMA: B[k][edge] = coords (h=0: x0,x1,x2,0; h=1: 0) ----
    short4v bx;
    {
      uint2v u;
      u[0] = h ? 0u : packc(x0, x1);
      u[1] = h ? 0u : packc(x2, 0.f);
      bx = __builtin_bit_cast(short4v, u);
    }
    f32x16 c;
    {
      const float4v* bb = (const float4v*)&sB1f[h][0];
      const float4v i0 = bb[0], i1 = bb[1], i2 = bb[2], i3 = bb[3];
#pragma unroll
      for (int e = 0; e < 4; ++e) {
        c[e] = i0[e]; c[4 + e] = i1[e]; c[8 + e] = i2[e]; c[12 + e] = i3[e];
      }
    }
    c = mfma32(a1, bx, c);

    float hv[16];
#pragma unroll
    for (int r = 0; r < 16; ++r) hv[r] = c[r];
    short4v bh[4];
    ln_relu_pack32f(hv, &sG1[h][0], &sBe1[h][0], bh);

    // ---- L2 GEMM: 32 -> 32 (K=32 via 4 segments) ----
    {
      const float4v* bb = (const float4v*)&sB2f[h][0];
      const float4v i0 = bb[0], i1 = bb[1], i2 = bb[2], i3 = bb[3];
#pragma unroll
      for (int e = 0; e < 4; ++e) {
        c[e] = i0[e]; c[4 + e] = i1[e]; c[8 + e] = i2[e]; c[12 + e] = i3[e];
      }
    }
#pragma unroll
    for (int s = 0; s < 4; ++s) c = mfma32(a2[s], bh[s], c);

#pragma unroll
    for (int r = 0; r < 16; ++r) hv[r] = c[r];
    ln_relu_pack32f(hv, &sG2[h][0], &sBe2[h][0], bh);

    // ---- prefetch next tile's feature gather (ieN landed) ----
    float4v f4aN = {}, f4bN = {};
    if (tn < ntiles) {
      f4aN = *(const float4v*)(ef + (size_t)ieN * 16 + 4 * h);
      f4bN = *(const float4v*)(ef + (size_t)ieN * 16 + 8 + 4 * h);
    }

    // lane-half partial of sum_i f[i] (completed by the pr shfl_xor(32))
    const float sumf = (f4a[0] + f4a[1]) + (f4a[2] + f4a[3])
                     + (f4b[0] + f4b[1]) + (f4b[2] + f4b[3]);

    // ---- L3: 8 m-tiles (2 o's each), K=32; tanh-algebra epilogue ----
    // unroll 1: bounds scheduler load-hoisting (R18 spill, R19 fix)
#pragma unroll 1
    for (int mt = 0; mt < 8; ++mt) {
      const uint4v av0 = *(const uint4v*)&sA3[mt * 512 + (l << 2)];
      const uint4v av1 = *(const uint4v*)&sA3[mt * 512 + 256 + (l << 2)];
      f32x16 c3;
      {
        const float4v i0 = *(const float4v*)&sB3f[(2 * mt) * 16 + 4 * h];
        const float4v i1 = *(const float4v*)&sB3f[(2 * mt) * 16 + 8 + 4 * h];
        const float4v i2 = *(const float4v*)&sB3f[(2 * mt + 1) * 16 + 4 * h];
        const float4v i3 = *(const float4v*)&sB3f[(2 * mt + 1) * 16 + 8 + 4 * h];
#pragma unroll
        for (int e = 0; e < 4; ++e) {
          c3[e] = i0[e]; c3[4 + e] = i1[e]; c3[8 + e] = i2[e]; c3[12 + e] = i3[e];
        }
      }
      uint2v u01, u23;
      u01[0] = av0[0]; u01[1] = av0[1];  u23[0] = av0[2]; u23[1] = av0[3];
      c3 = mfma32(__builtin_bit_cast(short4v, u01), bh[0], c3);
      c3 = mfma32(__builtin_bit_cast(short4v, u23), bh[1], c3);
      u01[0] = av1[0]; u01[1] = av1[1];  u23[0] = av1[2]; u23[1] = av1[3];
      c3 = mfma32(__builtin_bit_cast(short4v, u01), bh[2], c3);
      c3 = mfma32(__builtin_bit_cast(short4v, u23), bh[3], c3);

      float dot0 = 0.f, dot1 = 0.f;
#pragma unroll
      for (int j = 0; j < 4; ++j) {
        dot0 = fmaf(f4a[j], sigm2(c3[j]),      dot0);
        dot0 = fmaf(f4b[j], sigm2(c3[4 + j]),  dot0);
        dot1 = fmaf(f4a[j], sigm2(c3[8 + j]),  dot1);
        dot1 = fmaf(f4b[j], sigm2(c3[12 + j]), dot1);
      }
      float pr0 = fmaf(-2.0f, dot0, sumf);
      float pr1 = fmaf(-2.0f, dot1, sumf);
      pr0 += __shfl_xor(pr0, 32);
      pr1 += __shfl_xor(pr1, 32);

      if (SCATTER_MODE == 0) {
        if (h == 0 && valid)
          ((unsigned*)out_ch)[(size_t)pos * 8 + mt] = packc(pr0, pr1);
      } else {
        if (h == 0 && valid) {
          float* sums = (float*)out_ch;
          atomicAdd(&sums[(size_t)oe * 16 + 2 * mt],     pr0);
          atomicAdd(&sums[(size_t)oe * 16 + 2 * mt + 1], pr1);
        }
      }
    }
    if (SCATTER_MODE == 1) {
      if (h == 0 && valid) atomicAdd(&aux[oe], 1);
    }

    // rotate pipeline state
    valid = validN; oe = oeN;
    x0 = x0N; x1 = x1N; x2 = x2N; f4a = f4aN; f4b = f4bN;
  }
}

// ---------------- per-node reduce (CSR path, bf16 rows; R17-verified) ----------------

__global__ __launch_bounds__(256)
void nf_reduce(const uint4v* __restrict__ out_chb4, const int* __restrict__ counts,
               const int* __restrict__ offsets, float* __restrict__ out, int N) {
  const int gid  = blockIdx.x * 128 + (threadIdx.x >> 1);  // node
  const int half = threadIdx.x & 1;                        // channels 8h..8h+7
  if (gid >= N) return;
  const int deg = counts[gid];
  const int off = offsets[gid];
  float a[8] = {0.f, 0.f, 0.f, 0.f, 0.f, 0.f, 0.f, 0.f};
  for (int d = 0; d < deg; ++d) {
    const uint4v u = out_chb4[(size_t)(off + d) * 2 + half];
#pragma unroll
    for (int p = 0; p < 4; ++p) {
      a[2 * p]     += bflo2f(u[p]);
      a[2 * p + 1] += bfhi2f(u[p]);
    }
  }
  const float inv = 1.0f / fmaxf((float)deg, 1.0f);
  float4v r0, r1;
#pragma unroll
  for (int p = 0; p < 4; ++p) { r0[p] = a[p] * inv; r1[p] = a[4 + p] * inv; }
  float* dst = out + (size_t)gid * 16 + 8 * half;
  *(float4v*)dst       = r0;
  *(float4v*)(dst + 4) = r1;
}

// fallback divide
__global__ void nf_final(float* __restrict__ out, const int* __restrict__ counts, int n) {
  int i = blockIdx.x * blockDim.x + threadIdx.x;
  if (i < n) {
    float c = (float)counts[i >> 4];
    out[i] = out[i] / fmaxf(c, 1.0f);
  }
}

extern "C" void kernel_launch(void* const* d_in, const int* in_sizes, int n_in,
                              void* d_out, int out_size, void* d_ws, size_t ws_size,
                              hipStream_t stream) {
  const int*   in_edges  = (const int*)d_in[0];
  const int*   out_edges = (const int*)d_in[1];
  const float* ef        = (const float*)d_in[2];
  const float* coords    = (const float*)d_in[3];
  const float* W1  = (const float*)d_in[4];
  const float* b1  = (const float*)d_in[5];
  const float* g1  = (const float*)d_in[6];
  const float* be1 = (const float*)d_in[7];
  const float* W2  = (const float*)d_in[8];
  const float* b2  = (const float*)d_in[9];
  const float* g2  = (const float*)d_in[10];
  const float* be2 = (const float*)d_in[11];
  const float* W3  = (const float*)d_in[12];
  const float* b3  = (const float*)d_in[13];

  const int E = in_sizes[0];
  const int N = in_sizes[2] / 16;
  const int ntiles = (E + 31) / 32;
  float* out = (float*)d_out;

  // ws: out_chb [8E u32 bf16x2] | counts [N] | total [1] | offsets [N] | cursor [N]
  const size_t need = ((size_t)E * 8 + 3 * (size_t)N + 1) * 4;

  if (ws_size >= need) {
    unsigned* out_chb = (unsigned*)d_ws;
    int*      counts  = (int*)(out_chb + (size_t)E * 8);
    int*      total   = counts + N;
    int*      offsets = total + 1;
    int*      cursor  = offsets + N;

    (void)hipMemsetAsync(counts, 0, ((size_t)N + 1) * sizeof(int), stream);
    nf_hist<<<(E / 4 + 255) / 256 + 1, 256, 0, stream>>>(out_edges, counts, E);
    nf_alloc<<<(N + 255) / 256, 256, 0, stream>>>(counts, offsets, cursor, total, N);
    nf_main<0><<<1024, 256, 0, stream>>>(in_edges, out_edges, ef, coords,
                                         W1, b1, g1, be1, W2, b2, g2, be2, W3, b3,
                                         out_chb, nullptr, cursor, E, ntiles);
    nf_reduce<<<(N + 127) / 128, 256, 0, stream>>>((const uint4v*)out_chb, counts,
                                                   offsets, out, N);
  } else {
    // fallback: direct f32 atomics
    int* counts = (int*)d_ws;
    (void)hipMemsetAsync(out, 0, (size_t)out_size * sizeof(float), stream);
    (void)hipMemsetAsync(counts, 0, (size_t)N * sizeof(int), stream);
    nf_main<1><<<1024, 256, 0, stream>>>(in_edges, out_edges, ef, coords,
                                         W1, b1, g1, be1, W2, b2, g2, be2, W3, b3,
                                         out, counts, nullptr, E, ntiles);
    nf_final<<<(out_size + 255) / 256, 256, 0, stream>>>(out, counts, out_size);
  }
}

// Round 21
// 176.633 us; speedup vs baseline: 3.0199x; 1.0164x over previous
//
#include <hip/hip_runtime.h>
#include <hip/hip_bf16.h>

// NeuralFieldCosmo — R21: R20 byte-identical kernels; ONE change: nf_main
// grid 1024 -> 1536 (6 blocks/CU). R20 dropped VGPR 112->84, crossing into
// the 6-waves/SIMD band (512-reg budget / 84 ≈ 6), but grid 1024 left 2
// wave slots per SIMD empty. Kernel is latency-bound (VALUBusy 55%, MFMA
// 13%, DS/HBM low) -> more resident waves = more independent chains.
// LDS 6 x 18.4KB = 110KB <= 160KB: not a limiter.
// Ledger: raw cvt_pk asm banned. f2bf + packc verified. 32x32x8 A/B/C
// layouts verified R18-R20. unroll-1 epilogue = spill fix (R19).
// Spill tell = FETCH > 150 MB.

typedef __attribute__((ext_vector_type(4)))  short    short4v;  // 4 bf16 (2 VGPR)
typedef __attribute__((ext_vector_type(4)))  float    float4v;
typedef __attribute__((ext_vector_type(16))) float    f32x16;
typedef __attribute__((ext_vector_type(4)))  unsigned uint4v;
typedef __attribute__((ext_vector_type(2)))  unsigned uint2v;

constexpr float LN_EPS   = 1e-5f;
constexpr float LOG2E_X2 = 2.8853900817779268f;  // 2*log2(e)

// RNE float -> bf16 bits (staging; verified R4-R20)
__device__ __forceinline__ unsigned f2bf(float x) {
  unsigned u = __builtin_bit_cast(unsigned, x);
  u += 0x7FFFu + ((u >> 16) & 1u);
  return u >> 16;
}
__device__ __forceinline__ unsigned pack2(float lo, float hi) {
  return f2bf(lo) | (f2bf(hi) << 16);
}
// HOT pack: library bf16x2 cvt (RNE), low 16 bits = lo. Verified R16-R20.
__device__ __forceinline__ unsigned packc(float lo, float hi) {
  float2 v; v.x = lo; v.y = hi;
  const __hip_bfloat162 b = __float22bfloat162_rn(v);
  static_assert(sizeof(__hip_bfloat162) == 4, "bf16x2 must be 4 bytes");
  unsigned r;
  __builtin_memcpy(&r, &b, 4);
  return r;
}
__device__ __forceinline__ float bflo2f(unsigned u) {
  return __builtin_bit_cast(float, u << 16);
}
__device__ __forceinline__ float bfhi2f(unsigned u) {
  return __builtin_bit_cast(float, u & 0xFFFF0000u);
}
// rcp(exp2(x)+1)
__device__ __forceinline__ float sigm2(float x) {
  return __builtin_amdgcn_rcpf(__builtin_amdgcn_exp2f(x) + 1.0f);
}

__device__ __forceinline__ f32x16 mfma32(short4v a, short4v b, f32x16 c) {
#if __has_builtin(__builtin_amdgcn_mfma_f32_32x32x8bf16_1k)
  return __builtin_amdgcn_mfma_f32_32x32x8bf16_1k(a, b, c, 0, 0, 0);
#else
  asm volatile("v_mfma_f32_32x32x8_bf16 %0, %1, %2, %0\n\ts_nop 7\n\ts_nop 7"
               : "+v"(c) : "v"(a), "v"(b));
  return c;
#endif
}

// LN over 32 chs (16/lane; lane^32 holds complement), affine from f32 LDS
// (broadcast reads), relu, pack to 4 B-frag K-segments via packc.
__device__ __forceinline__ void ln_relu_pack32f(const float* hv,
                                                const float* __restrict__ gf,
                                                const float* __restrict__ bef,
                                                short4v* bh) {
  float sum = 0.f, ss = 0.f;
#pragma unroll
  for (int i = 0; i < 16; ++i) { sum += hv[i]; ss += hv[i] * hv[i]; }
  sum += __shfl_xor(sum, 32);
  ss  += __shfl_xor(ss, 32);
  const float m   = sum * (1.0f / 32.0f);
  const float var = fmaxf(ss * (1.0f / 32.0f) - m * m, 0.f);
  const float rs  = rsqrtf(var + LN_EPS);
#pragma unroll
  for (int s = 0; s < 4; ++s) {
    const float4v gv = *(const float4v*)&gf[s * 4];
    const float4v bv = *(const float4v*)&bef[s * 4];
    float y[4];
#pragma unroll
    for (int j = 0; j < 4; ++j)
      y[j] = fmaxf((hv[s * 4 + j] - m) * rs * gv[j] + bv[j], 0.f);
    uint2v u; u[0] = packc(y[0], y[1]); u[1] = packc(y[2], y[3]);
    bh[s] = __builtin_bit_cast(short4v, u);
  }
}

// ---------------- CSR build (R17-verified) ----------------

__global__ void nf_hist(const int* __restrict__ out_edges, int* __restrict__ counts, int E) {
  const int t4 = (blockIdx.x * blockDim.x + threadIdx.x) * 4;
  if (t4 + 3 < E) {
    const int4 v = *(const int4*)(out_edges + t4);
    atomicAdd(&counts[v.x], 1);
    atomicAdd(&counts[v.y], 1);
    atomicAdd(&counts[v.z], 1);
    atomicAdd(&counts[v.w], 1);
  } else {
    for (int i = t4; i < E; ++i) atomicAdd(&counts[out_edges[i]], 1);
  }
}

__global__ void nf_alloc(const int* __restrict__ counts, int* __restrict__ offsets,
                         int* __restrict__ cursor, int* __restrict__ total, int N) {
  const int i = blockIdx.x * blockDim.x + threadIdx.x;
  const int lane = threadIdx.x & 63;
  int c = (i < N) ? counts[i] : 0;
  int sc = c;
#pragma unroll
  for (int d = 1; d < 64; d <<= 1) {
    int v = __shfl_up(sc, d);
    if (lane >= d) sc += v;
  }
  const int excl = sc - c;
  const int wtot = __shfl(sc, 63);
  int base = 0;
  if (lane == 0) base = atomicAdd(total, wtot);
  base = __shfl(base, 0);
  if (i < N) {
    offsets[i] = base + excl;
    cursor[i]  = base + excl;
  }
}

// ---------------- main compute ----------------
// SCATTER_MODE: 0 = CSR-ordered bf16 stream, 1 = direct f32 atomics fallback

template <int SCATTER_MODE>
__global__ __launch_bounds__(256, 2)
void nf_main(const int* __restrict__ in_edges,
             const int* __restrict__ out_edges,
             const float* __restrict__ ef,
             const float* __restrict__ coords,
             const float* __restrict__ W1, const float* __restrict__ b1,
             const float* __restrict__ g1, const float* __restrict__ be1,
             const float* __restrict__ W2, const float* __restrict__ b2,
             const float* __restrict__ g2, const float* __restrict__ be2,
             const float* __restrict__ W3, const float* __restrict__ b3,
             void* __restrict__ out_ch,   // mode0: unsigned[E][8] bf16x2 ; mode1: float sums (d_out)
             int* __restrict__ aux,       // mode1: counts
             int* __restrict__ cursor,    // mode0: [N]
             int E, int ntiles)
{
  // W3 A-frags (prescaled 2log2e): [mt][blk][lane][4 u32]  (16 KB)
  __shared__ __align__(16) unsigned sA3[8 * 2 * 64 * 4];
  __shared__ __align__(16) float    sB3f[256];     // 2log2e*b3, [o][i]
  __shared__ __align__(16) float    sB2f[2][16];   // b2 in C-row order
  // f32 per-h lane-channel consts, hv order (idx s*4+j <-> ch 8s+4h+j)
  __shared__ __align__(16) float    sB1f[2][16];
  __shared__ __align__(16) float    sG1[2][16],  sBe1[2][16];
  __shared__ __align__(16) float    sG2[2][16],  sBe2[2][16];

  const int t    = threadIdx.x;
  const int l    = t & 63;
  const int h    = l >> 5;     // half: k-group / C-row group
  const int ecol = l & 31;     // edge column within 32-edge tile

  // ---- one-time LDS staging (sA3/sB3f R18-verified) ----
#pragma unroll
  for (int rep = 0; rep < 16; ++rep) {
    const int idx = rep * 256 + t;
    const int u = idx & 3, ll = (idx >> 2) & 63, b = (idx >> 8) & 1, mt = idx >> 9;
    const int s = b * 2 + (u >> 1), jp = u & 1;
    const int hh = ll >> 5, m = ll & 31;
    const int o = 2 * mt + (m >> 4), i = m & 15;
    const int k0 = 8 * s + 4 * hh + 2 * jp;
    sA3[idx] = pack2(LOG2E_X2 * W3[(size_t)k0 * 256 + o * 16 + i],
                     LOG2E_X2 * W3[(size_t)(k0 + 1) * 256 + o * 16 + i]);
  }
  sB3f[t] = LOG2E_X2 * b3[t];
  if (t < 32) {
    const int hh = t >> 4, r = t & 15;          // r = s*4+j
    const int ch = 8 * (r >> 2) + 4 * hh + (r & 3);
    sB2f[hh][r] = b2[ch];
    sB1f[hh][r] = b1[ch];
    sG1[hh][r]  = g1[ch];   sBe1[hh][r] = be1[ch];
    sG2[hh][r]  = g2[ch];   sBe2[hh][r] = be2[ch];
  }

  // L1 A-frag (1 reg-pair): A[m=ch_out=ecol][k=4h+j] = W1[k][ecol], k<3
  short4v a1;
#pragma unroll
  for (int j = 0; j < 4; ++j) {
    const int k = 4 * h + j;
    a1[j] = (k < 3) ? (short)f2bf(W1[k * 32 + ecol]) : (short)0;
  }
  // L2 A-frags (8 VGPR): A[m=ecol][k=8s+4h+j] = W2[k][ecol]
  short4v a2[4];
#pragma unroll
  for (int s = 0; s < 4; ++s) {
    short4v v;
#pragma unroll
    for (int j = 0; j < 4; ++j)
      v[j] = (short)f2bf(W2[(8 * s + 4 * h + j) * 32 + ecol]);
    a2[s] = v;
  }
  __syncthreads();

  const int gwave  = (blockIdx.x * blockDim.x + t) >> 6;
  const int nwaves = (gridDim.x * blockDim.x) >> 6;

  // ---- prologue: tile-0 state ----
  int tile = gwave;
  bool valid = false; int oe = 0;
  float x0 = 0.f, x1 = 0.f, x2 = 0.f;
  float4v f4a = {}, f4b = {};
  if (tile < ntiles) {
    const int eIdx = tile * 32 + ecol;
    valid = eIdx < E;
    const int eS = valid ? eIdx : 0;
    const int ie = in_edges[eS]; oe = out_edges[eS];
    x0 = coords[3 * eS]; x1 = coords[3 * eS + 1]; x2 = coords[3 * eS + 2];
    f4a = *(const float4v*)(ef + (size_t)ie * 16 + 4 * h);
    f4b = *(const float4v*)(ef + (size_t)ie * 16 + 8 + 4 * h);
  }

  for (; tile < ntiles; tile += nwaves) {
    // ---- prefetch next tile indices + coords ----
    const int tn = tile + nwaves;
    int ieN = 0, oeN = 0; bool validN = false;
    float x0N = 0.f, x1N = 0.f, x2N = 0.f;
    if (tn < ntiles) {
      const int eIdxN = tn * 32 + ecol;
      validN = eIdxN < E;
      const int eSN = validN ? eIdxN : 0;
      ieN = in_edges[eSN]; oeN = out_edges[eSN];
      x0N = coords[3 * eSN]; x1N = coords[3 * eSN + 1]; x2N = coords[3 * eSN + 2];
    }

    // CSR slot (atomic latency hides under MLP)
    int pos = 0;
    if (SCATTER_MODE == 0 && h == 0 && valid)
      pos = atomicAdd(&cursor[oe], 1);

    // ---- L1 as one MFMA: B[k][edge] = coords (h=0: x0,x1,x2,0; h=1: 0) ----
    short4v bx;
    {
      uint2v u;
      u[0] = h ? 0u : packc(x0, x1);
      u[1] = h ? 0u : packc(x2, 0.f);
      bx = __builtin_bit_cast(short4v, u);
    }
    f32x16 c;
    {
      const float4v* bb = (const float4v*)&sB1f[h][0];
      const float4v i0 = bb[0], i1 = bb[1], i2 = bb[2], i3 = bb[3];
#pragma unroll
      for (int e = 0; e < 4; ++e) {
        c[e] = i0[e]; c[4 + e] = i1[e]; c[8 + e] = i2[e]; c[12 + e] = i3[e];
      }
    }
    c = mfma32(a1, bx, c);

    float hv[16];
#pragma unroll
    for (int r = 0; r < 16; ++r) hv[r] = c[r];
    short4v bh[4];
    ln_relu_pack32f(hv, &sG1[h][0], &sBe1[h][0], bh);

    // ---- L2 GEMM: 32 -> 32 (K=32 via 4 segments) ----
    {
      const float4v* bb = (const float4v*)&sB2f[h][0];
      const float4v i0 = bb[0], i1 = bb[1], i2 = bb[2], i3 = bb[3];
#pragma unroll
      for (int e = 0; e < 4; ++e) {
        c[e] = i0[e]; c[4 + e] = i1[e]; c[8 + e] = i2[e]; c[12 + e] = i3[e];
      }
    }
#pragma unroll
    for (int s = 0; s < 4; ++s) c = mfma32(a2[s], bh[s], c);

#pragma unroll
    for (int r = 0; r < 16; ++r) hv[r] = c[r];
    ln_relu_pack32f(hv, &sG2[h][0], &sBe2[h][0], bh);

    // ---- prefetch next tile's feature gather (ieN landed) ----
    float4v f4aN = {}, f4bN = {};
    if (tn < ntiles) {
      f4aN = *(const float4v*)(ef + (size_t)ieN * 16 + 4 * h);
      f4bN = *(const float4v*)(ef + (size_t)ieN * 16 + 8 + 4 * h);
    }

    // lane-half partial of sum_i f[i] (completed by the pr shfl_xor(32))
    const float sumf = (f4a[0] + f4a[1]) + (f4a[2] + f4a[3])
                     + (f4b[0] + f4b[1]) + (f4b[2] + f4b[3]);

    // ---- L3: 8 m-tiles (2 o's each), K=32; tanh-algebra epilogue ----
    // unroll 1: bounds scheduler load-hoisting (R18 spill, R19 fix)
#pragma unroll 1
    for (int mt = 0; mt < 8; ++mt) {
      const uint4v av0 = *(const uint4v*)&sA3[mt * 512 + (l << 2)];
      const uint4v av1 = *(const uint4v*)&sA3[mt * 512 + 256 + (l << 2)];
      f32x16 c3;
      {
        const float4v i0 = *(const float4v*)&sB3f[(2 * mt) * 16 + 4 * h];
        const float4v i1 = *(const float4v*)&sB3f[(2 * mt) * 16 + 8 + 4 * h];
        const float4v i2 = *(const float4v*)&sB3f[(2 * mt + 1) * 16 + 4 * h];
        const float4v i3 = *(const float4v*)&sB3f[(2 * mt + 1) * 16 + 8 + 4 * h];
#pragma unroll
        for (int e = 0; e < 4; ++e) {
          c3[e] = i0[e]; c3[4 + e] = i1[e]; c3[8 + e] = i2[e]; c3[12 + e] = i3[e];
        }
      }
      uint2v u01, u23;
      u01[0] = av0[0]; u01[1] = av0[1];  u23[0] = av0[2]; u23[1] = av0[3];
      c3 = mfma32(__builtin_bit_cast(short4v, u01), bh[0], c3);
      c3 = mfma32(__builtin_bit_cast(short4v, u23), bh[1], c3);
      u01[0] = av1[0]; u01[1] = av1[1];  u23[0] = av1[2]; u23[1] = av1[3];
      c3 = mfma32(__builtin_bit_cast(short4v, u01), bh[2], c3);
      c3 = mfma32(__builtin_bit_cast(short4v, u23), bh[3], c3);

      float dot0 = 0.f, dot1 = 0.f;
#pragma unroll
      for (int j = 0; j < 4; ++j) {
        dot0 = fmaf(f4a[j], sigm2(c3[j]),      dot0);
        dot0 = fmaf(f4b[j], sigm2(c3[4 + j]),  dot0);
        dot1 = fmaf(f4a[j], sigm2(c3[8 + j]),  dot1);
        dot1 = fmaf(f4b[j], sigm2(c3[12 + j]), dot1);
      }
      float pr0 = fmaf(-2.0f, dot0, sumf);
      float pr1 = fmaf(-2.0f, dot1, sumf);
      pr0 += __shfl_xor(pr0, 32);
      pr1 += __shfl_xor(pr1, 32);

      if (SCATTER_MODE == 0) {
        if (h == 0 && valid)
          ((unsigned*)out_ch)[(size_t)pos * 8 + mt] = packc(pr0, pr1);
      } else {
        if (h == 0 && valid) {
          float* sums = (float*)out_ch;
          atomicAdd(&sums[(size_t)oe * 16 + 2 * mt],     pr0);
          atomicAdd(&sums[(size_t)oe * 16 + 2 * mt + 1], pr1);
        }
      }
    }
    if (SCATTER_MODE == 1) {
      if (h == 0 && valid) atomicAdd(&aux[oe], 1);
    }

    // rotate pipeline state
    valid = validN; oe = oeN;
    x0 = x0N; x1 = x1N; x2 = x2N; f4a = f4aN; f4b = f4bN;
  }
}

// ---------------- per-node reduce (CSR path, bf16 rows; R17-verified) ----------------

__global__ __launch_bounds__(256)
void nf_reduce(const uint4v* __restrict__ out_chb4, const int* __restrict__ counts,
               const int* __restrict__ offsets, float* __restrict__ out, int N) {
  const int gid  = blockIdx.x * 128 + (threadIdx.x >> 1);  // node
  const int half = threadIdx.x & 1;                        // channels 8h..8h+7
  if (gid >= N) return;
  const int deg = counts[gid];
  const int off = offsets[gid];
  float a[8] = {0.f, 0.f, 0.f, 0.f, 0.f, 0.f, 0.f, 0.f};
  for (int d = 0; d < deg; ++d) {
    const uint4v u = out_chb4[(size_t)(off + d) * 2 + half];
#pragma unroll
    for (int p = 0; p < 4; ++p) {
      a[2 * p]     += bflo2f(u[p]);
      a[2 * p + 1] += bfhi2f(u[p]);
    }
  }
  const float inv = 1.0f / fmaxf((float)deg, 1.0f);
  float4v r0, r1;
#pragma unroll
  for (int p = 0; p < 4; ++p) { r0[p] = a[p] * inv; r1[p] = a[4 + p] * inv; }
  float* dst = out + (size_t)gid * 16 + 8 * half;
  *(float4v*)dst       = r0;
  *(float4v*)(dst + 4) = r1;
}

// fallback divide
__global__ void nf_final(float* __restrict__ out, const int* __restrict__ counts, int n) {
  int i = blockIdx.x * blockDim.x + threadIdx.x;
  if (i < n) {
    float c = (float)counts[i >> 4];
    out[i] = out[i] / fmaxf(c, 1.0f);
  }
}

extern "C" void kernel_launch(void* const* d_in, const int* in_sizes, int n_in,
                              void* d_out, int out_size, void* d_ws, size_t ws_size,
                              hipStream_t stream) {
  const int*   in_edges  = (const int*)d_in[0];
  const int*   out_edges = (const int*)d_in[1];
  const float* ef        = (const float*)d_in[2];
  const float* coords    = (const float*)d_in[3];
  const float* W1  = (const float*)d_in[4];
  const float* b1  = (const float*)d_in[5];
  const float* g1  = (const float*)d_in[6];
  const float* be1 = (const float*)d_in[7];
  const float* W2  = (const float*)d_in[8];
  const float* b2  = (const float*)d_in[9];
  const float* g2  = (const float*)d_in[10];
  const float* be2 = (const float*)d_in[11];
  const float* W3  = (const float*)d_in[12];
  const float* b3  = (const float*)d_in[13];

  const int E = in_sizes[0];
  const int N = in_sizes[2] / 16;
  const int ntiles = (E + 31) / 32;
  float* out = (float*)d_out;

  // ws: out_chb [8E u32 bf16x2] | counts [N] | total [1] | offsets [N] | cursor [N]
  const size_t need = ((size_t)E * 8 + 3 * (size_t)N + 1) * 4;

  if (ws_size >= need) {
    unsigned* out_chb = (unsigned*)d_ws;
    int*      counts  = (int*)(out_chb + (size_t)E * 8);
    int*      total   = counts + N;
    int*      offsets = total + 1;
    int*      cursor  = offsets + N;

    (void)hipMemsetAsync(counts, 0, ((size_t)N + 1) * sizeof(int), stream);
    nf_hist<<<(E / 4 + 255) / 256 + 1, 256, 0, stream>>>(out_edges, counts, E);
    nf_alloc<<<(N + 255) / 256, 256, 0, stream>>>(counts, offsets, cursor, total, N);
    nf_main<0><<<1536, 256, 0, stream>>>(in_edges, out_edges, ef, coords,
                                         W1, b1, g1, be1, W2, b2, g2, be2, W3, b3,
                                         out_chb, nullptr, cursor, E, ntiles);
    nf_reduce<<<(N + 127) / 128, 256, 0, stream>>>((const uint4v*)out_chb, counts,
                                                   offsets, out, N);
  } else {
    // fallback: direct f32 atomics
    int* counts = (int*)d_ws;
    (void)hipMemsetAsync(out, 0, (size_t)out_size * sizeof(float), stream);
    (void)hipMemsetAsync(counts, 0, (size_t)N * sizeof(int), stream);
    nf_main<1><<<1536, 256, 0, stream>>>(in_edges, out_edges, ef, coords,
                                         W1, b1, g1, be1, W2, b2, g2, be2, W3, b3,
                                         out, counts, nullptr, E, ntiles);
    nf_final<<<(out_size + 255) / 256, 256, 0, stream>>>(out, counts, out_size);
  }
}

// Round 22
// 172.073 us; speedup vs baseline: 3.0999x; 1.0265x over previous
//
#include <hip/hip_runtime.h>
#include <hip/hip_bf16.h>

// NeuralFieldCosmo — R22: R21 base (verified 176.6us, absmax 0.04296875) +
// SKEWED PIPELINE on the 32x32 formulation: loop body = front(t+1) ∥
// epilogue(t) (R14-proven pattern, -8% on the 16x16 base at constant
// occupancy). R21 lesson: VGPR bands quantize at 64/128/256 -> 84 VGPR is
// in the 65-128 band (4 waves/SIMD cap); +22 carried regs (bhN, f4N, t+2
// idx/coords) are FREE within the band.
// Ledger: raw cvt_pk asm banned. f2bf + packc verified. 32x32x8 A/B/C
// layouts verified R18-R21. unroll-1 epilogue = spill fix (R19).
// Spill tell = FETCH > 150 MB -> revert R21, declare roofline.

typedef __attribute__((ext_vector_type(4)))  short    short4v;  // 4 bf16 (2 VGPR)
typedef __attribute__((ext_vector_type(4)))  float    float4v;
typedef __attribute__((ext_vector_type(16))) float    f32x16;
typedef __attribute__((ext_vector_type(4)))  unsigned uint4v;
typedef __attribute__((ext_vector_type(2)))  unsigned uint2v;

constexpr float LN_EPS   = 1e-5f;
constexpr float LOG2E_X2 = 2.8853900817779268f;  // 2*log2(e)

// RNE float -> bf16 bits (staging; verified R4-R21)
__device__ __forceinline__ unsigned f2bf(float x) {
  unsigned u = __builtin_bit_cast(unsigned, x);
  u += 0x7FFFu + ((u >> 16) & 1u);
  return u >> 16;
}
__device__ __forceinline__ unsigned pack2(float lo, float hi) {
  return f2bf(lo) | (f2bf(hi) << 16);
}
// HOT pack: library bf16x2 cvt (RNE), low 16 bits = lo. Verified R16-R21.
__device__ __forceinline__ unsigned packc(float lo, float hi) {
  float2 v; v.x = lo; v.y = hi;
  const __hip_bfloat162 b = __float22bfloat162_rn(v);
  static_assert(sizeof(__hip_bfloat162) == 4, "bf16x2 must be 4 bytes");
  unsigned r;
  __builtin_memcpy(&r, &b, 4);
  return r;
}
__device__ __forceinline__ float bflo2f(unsigned u) {
  return __builtin_bit_cast(float, u << 16);
}
__device__ __forceinline__ float bfhi2f(unsigned u) {
  return __builtin_bit_cast(float, u & 0xFFFF0000u);
}
// rcp(exp2(x)+1)
__device__ __forceinline__ float sigm2(float x) {
  return __builtin_amdgcn_rcpf(__builtin_amdgcn_exp2f(x) + 1.0f);
}

__device__ __forceinline__ f32x16 mfma32(short4v a, short4v b, f32x16 c) {
#if __has_builtin(__builtin_amdgcn_mfma_f32_32x32x8bf16_1k)
  return __builtin_amdgcn_mfma_f32_32x32x8bf16_1k(a, b, c, 0, 0, 0);
#else
  asm volatile("v_mfma_f32_32x32x8_bf16 %0, %1, %2, %0\n\ts_nop 7\n\ts_nop 7"
               : "+v"(c) : "v"(a), "v"(b));
  return c;
#endif
}

// LN over 32 chs (16/lane; lane^32 holds complement), affine from f32 LDS
// (broadcast reads), relu, pack to 4 B-frag K-segments via packc.
__device__ __forceinline__ void ln_relu_pack32f(const float* hv,
                                                const float* __restrict__ gf,
                                                const float* __restrict__ bef,
                                                short4v* bh) {
  float sum = 0.f, ss = 0.f;
#pragma unroll
  for (int i = 0; i < 16; ++i) { sum += hv[i]; ss += hv[i] * hv[i]; }
  sum += __shfl_xor(sum, 32);
  ss  += __shfl_xor(ss, 32);
  const float m   = sum * (1.0f / 32.0f);
  const float var = fmaxf(ss * (1.0f / 32.0f) - m * m, 0.f);
  const float rs  = rsqrtf(var + LN_EPS);
#pragma unroll
  for (int s = 0; s < 4; ++s) {
    const float4v gv = *(const float4v*)&gf[s * 4];
    const float4v bv = *(const float4v*)&bef[s * 4];
    float y[4];
#pragma unroll
    for (int j = 0; j < 4; ++j)
      y[j] = fmaxf((hv[s * 4 + j] - m) * rs * gv[j] + bv[j], 0.f);
    uint2v u; u[0] = packc(y[0], y[1]); u[1] = packc(y[2], y[3]);
    bh[s] = __builtin_bit_cast(short4v, u);
  }
}

// ---------------- CSR build (R17-verified) ----------------

__global__ void nf_hist(const int* __restrict__ out_edges, int* __restrict__ counts, int E) {
  const int t4 = (blockIdx.x * blockDim.x + threadIdx.x) * 4;
  if (t4 + 3 < E) {
    const int4 v = *(const int4*)(out_edges + t4);
    atomicAdd(&counts[v.x], 1);
    atomicAdd(&counts[v.y], 1);
    atomicAdd(&counts[v.z], 1);
    atomicAdd(&counts[v.w], 1);
  } else {
    for (int i = t4; i < E; ++i) atomicAdd(&counts[out_edges[i]], 1);
  }
}

__global__ void nf_alloc(const int* __restrict__ counts, int* __restrict__ offsets,
                         int* __restrict__ cursor, int* __restrict__ total, int N) {
  const int i = blockIdx.x * blockDim.x + threadIdx.x;
  const int lane = threadIdx.x & 63;
  int c = (i < N) ? counts[i] : 0;
  int sc = c;
#pragma unroll
  for (int d = 1; d < 64; d <<= 1) {
    int v = __shfl_up(sc, d);
    if (lane >= d) sc += v;
  }
  const int excl = sc - c;
  const int wtot = __shfl(sc, 63);
  int base = 0;
  if (lane == 0) base = atomicAdd(total, wtot);
  base = __shfl(base, 0);
  if (i < N) {
    offsets[i] = base + excl;
    cursor[i]  = base + excl;
  }
}

// ---------------- main compute ----------------
// SCATTER_MODE: 0 = CSR-ordered bf16 stream, 1 = direct f32 atomics fallback

template <int SCATTER_MODE>
__global__ __launch_bounds__(256, 2)
void nf_main(const int* __restrict__ in_edges,
             const int* __restrict__ out_edges,
             const float* __restrict__ ef,
             const float* __restrict__ coords,
             const float* __restrict__ W1, const float* __restrict__ b1,
             const float* __restrict__ g1, const float* __restrict__ be1,
             const float* __restrict__ W2, const float* __restrict__ b2,
             const float* __restrict__ g2, const float* __restrict__ be2,
             const float* __restrict__ W3, const float* __restrict__ b3,
             void* __restrict__ out_ch,   // mode0: unsigned[E][8] bf16x2 ; mode1: float sums (d_out)
             int* __restrict__ aux,       // mode1: counts
             int* __restrict__ cursor,    // mode0: [N]
             int E, int ntiles)
{
  // W3 A-frags (prescaled 2log2e): [mt][blk][lane][4 u32]  (16 KB)
  __shared__ __align__(16) unsigned sA3[8 * 2 * 64 * 4];
  __shared__ __align__(16) float    sB3f[256];     // 2log2e*b3, [o][i]
  __shared__ __align__(16) float    sB2f[2][16];   // b2 in C-row order
  // f32 per-h lane-channel consts, hv order (idx s*4+j <-> ch 8s+4h+j)
  __shared__ __align__(16) float    sB1f[2][16];
  __shared__ __align__(16) float    sG1[2][16],  sBe1[2][16];
  __shared__ __align__(16) float    sG2[2][16],  sBe2[2][16];

  const int t    = threadIdx.x;
  const int l    = t & 63;
  const int h    = l >> 5;     // half: k-group / C-row group
  const int ecol = l & 31;     // edge column within 32-edge tile

  // ---- one-time LDS staging (R18-R21 verified) ----
#pragma unroll
  for (int rep = 0; rep < 16; ++rep) {
    const int idx = rep * 256 + t;
    const int u = idx & 3, ll = (idx >> 2) & 63, b = (idx >> 8) & 1, mt = idx >> 9;
    const int s = b * 2 + (u >> 1), jp = u & 1;
    const int hh = ll >> 5, m = ll & 31;
    const int o = 2 * mt + (m >> 4), i = m & 15;
    const int k0 = 8 * s + 4 * hh + 2 * jp;
    sA3[idx] = pack2(LOG2E_X2 * W3[(size_t)k0 * 256 + o * 16 + i],
                     LOG2E_X2 * W3[(size_t)(k0 + 1) * 256 + o * 16 + i]);
  }
  sB3f[t] = LOG2E_X2 * b3[t];
  if (t < 32) {
    const int hh = t >> 4, r = t & 15;          // r = s*4+j
    const int ch = 8 * (r >> 2) + 4 * hh + (r & 3);
    sB2f[hh][r] = b2[ch];
    sB1f[hh][r] = b1[ch];
    sG1[hh][r]  = g1[ch];   sBe1[hh][r] = be1[ch];
    sG2[hh][r]  = g2[ch];   sBe2[hh][r] = be2[ch];
  }

  // L1 A-frag: A[m=ch_out=ecol][k=4h+j] = W1[k][ecol], k<3
  short4v a1;
#pragma unroll
  for (int j = 0; j < 4; ++j) {
    const int k = 4 * h + j;
    a1[j] = (k < 3) ? (short)f2bf(W1[k * 32 + ecol]) : (short)0;
  }
  // L2 A-frags (8 VGPR): A[m=ecol][k=8s+4h+j] = W2[k][ecol]
  short4v a2[4];
#pragma unroll
  for (int s = 0; s < 4; ++s) {
    short4v v;
#pragma unroll
    for (int j = 0; j < 4; ++j)
      v[j] = (short)f2bf(W2[(8 * s + 4 * h + j) * 32 + ecol]);
    a2[s] = v;
  }
  __syncthreads();

  // front: L1-MFMA -> LN1 -> L2 -> LN2 -> bh[4] (R20/R21 numerics)
  auto front = [&](float x0, float x1, float x2, short4v* bh) {
    short4v bx;
    {
      uint2v u;
      u[0] = h ? 0u : packc(x0, x1);
      u[1] = h ? 0u : packc(x2, 0.f);
      bx = __builtin_bit_cast(short4v, u);
    }
    f32x16 c;
    {
      const float4v* bb = (const float4v*)&sB1f[h][0];
      const float4v i0 = bb[0], i1 = bb[1], i2 = bb[2], i3 = bb[3];
#pragma unroll
      for (int e = 0; e < 4; ++e) {
        c[e] = i0[e]; c[4 + e] = i1[e]; c[8 + e] = i2[e]; c[12 + e] = i3[e];
      }
    }
    c = mfma32(a1, bx, c);

    float hv[16];
#pragma unroll
    for (int r = 0; r < 16; ++r) hv[r] = c[r];
    ln_relu_pack32f(hv, &sG1[h][0], &sBe1[h][0], bh);

    {
      const float4v* bb = (const float4v*)&sB2f[h][0];
      const float4v i0 = bb[0], i1 = bb[1], i2 = bb[2], i3 = bb[3];
#pragma unroll
      for (int e = 0; e < 4; ++e) {
        c[e] = i0[e]; c[4 + e] = i1[e]; c[8 + e] = i2[e]; c[12 + e] = i3[e];
      }
    }
#pragma unroll
    for (int s = 0; s < 4; ++s) c = mfma32(a2[s], bh[s], c);

#pragma unroll
    for (int r = 0; r < 16; ++r) hv[r] = c[r];
    ln_relu_pack32f(hv, &sG2[h][0], &sBe2[h][0], bh);
  };

  const int gwave  = (blockIdx.x * blockDim.x + t) >> 6;
  const int nwaves = (gridDim.x * blockDim.x) >> 6;

  // ---- skewed-pipeline prologue ----
  int tile = gwave;
  bool validC = false; int oeC = 0;
  short4v bhC[4] = {};
  float4v f4aC = {}, f4bC = {};
  bool validN = false; int ieN = 0, oeN = 0;
  float xN0 = 0.f, xN1 = 0.f, xN2 = 0.f;

  if (tile < ntiles) {
    const int eIdx = tile * 32 + ecol;
    validC = eIdx < E;
    const int eS = validC ? eIdx : 0;
    const int ie = in_edges[eS]; oeC = out_edges[eS];
    const float x0 = coords[3 * eS], x1 = coords[3 * eS + 1], x2 = coords[3 * eS + 2];
    f4aC = *(const float4v*)(ef + (size_t)ie * 16 + 4 * h);
    f4bC = *(const float4v*)(ef + (size_t)ie * 16 + 8 + 4 * h);
    front(x0, x1, x2, bhC);
  }
  if (tile + nwaves < ntiles) {
    const int eIdx = (tile + nwaves) * 32 + ecol;
    validN = eIdx < E;
    const int eS = validN ? eIdx : 0;
    ieN = in_edges[eS]; oeN = out_edges[eS];
    xN0 = coords[3 * eS]; xN1 = coords[3 * eS + 1]; xN2 = coords[3 * eS + 2];
  }

  for (; tile < ntiles; tile += nwaves) {
    const int tn  = tile + nwaves;       // tile whose front runs this iter
    const int tnn = tile + 2 * nwaves;   // tile whose idx/coords prefetch now

    // ---- issue next tile's feature gathers (consumed next iteration) ----
    float4v f4aN = {}, f4bN = {};
    if (tn < ntiles) {
      f4aN = *(const float4v*)(ef + (size_t)ieN * 16 + 4 * h);
      f4bN = *(const float4v*)(ef + (size_t)ieN * 16 + 8 + 4 * h);
    }

    // CSR slot for CURRENT tile (latency hides under front+epilogue)
    int pos = 0;
    if (SCATTER_MODE == 0 && h == 0 && validC)
      pos = atomicAdd(&cursor[oeC], 1);

    // ---- prefetch tile t+2 idx/coords ----
    bool validNN = false; int ieNN = 0, oeNN = 0;
    float xNN0 = 0.f, xNN1 = 0.f, xNN2 = 0.f;
    if (tnn < ntiles) {
      const int eIdx = tnn * 32 + ecol;
      validNN = eIdx < E;
      const int eS = validNN ? eIdx : 0;
      ieNN = in_edges[eS]; oeNN = out_edges[eS];
      xNN0 = coords[3 * eS]; xNN1 = coords[3 * eS + 1]; xNN2 = coords[3 * eS + 2];
    }

    // ---- front(t+1): serial MFMA/LN chains issue first... ----
    short4v bhN[4] = {};
    if (tn < ntiles)
      front(xN0, xN1, xN2, bhN);

    // ---- ...epilogue(t): independent trans/FMA stream fills the stalls ----
    const float sumf = (f4aC[0] + f4aC[1]) + (f4aC[2] + f4aC[3])
                     + (f4bC[0] + f4bC[1]) + (f4bC[2] + f4bC[3]);

    // unroll 1: bounds scheduler load-hoisting (R18 spill, R19 fix)
#pragma unroll 1
    for (int mt = 0; mt < 8; ++mt) {
      const uint4v av0 = *(const uint4v*)&sA3[mt * 512 + (l << 2)];
      const uint4v av1 = *(const uint4v*)&sA3[mt * 512 + 256 + (l << 2)];
      f32x16 c3;
      {
        const float4v i0 = *(const float4v*)&sB3f[(2 * mt) * 16 + 4 * h];
        const float4v i1 = *(const float4v*)&sB3f[(2 * mt) * 16 + 8 + 4 * h];
        const float4v i2 = *(const float4v*)&sB3f[(2 * mt + 1) * 16 + 4 * h];
        const float4v i3 = *(const float4v*)&sB3f[(2 * mt + 1) * 16 + 8 + 4 * h];
#pragma unroll
        for (int e = 0; e < 4; ++e) {
          c3[e] = i0[e]; c3[4 + e] = i1[e]; c3[8 + e] = i2[e]; c3[12 + e] = i3[e];
        }
      }
      uint2v u01, u23;
      u01[0] = av0[0]; u01[1] = av0[1];  u23[0] = av0[2]; u23[1] = av0[3];
      c3 = mfma32(__builtin_bit_cast(short4v, u01), bhC[0], c3);
      c3 = mfma32(__builtin_bit_cast(short4v, u23), bhC[1], c3);
      u01[0] = av1[0]; u01[1] = av1[1];  u23[0] = av1[2]; u23[1] = av1[3];
      c3 = mfma32(__builtin_bit_cast(short4v, u01), bhC[2], c3);
      c3 = mfma32(__builtin_bit_cast(short4v, u23), bhC[3], c3);

      float dot0 = 0.f, dot1 = 0.f;
#pragma unroll
      for (int j = 0; j < 4; ++j) {
        dot0 = fmaf(f4aC[j], sigm2(c3[j]),      dot0);
        dot0 = fmaf(f4bC[j], sigm2(c3[4 + j]),  dot0);
        dot1 = fmaf(f4aC[j], sigm2(c3[8 + j]),  dot1);
        dot1 = fmaf(f4bC[j], sigm2(c3[12 + j]), dot1);
      }
      float pr0 = fmaf(-2.0f, dot0, sumf);
      float pr1 = fmaf(-2.0f, dot1, sumf);
      pr0 += __shfl_xor(pr0, 32);
      pr1 += __shfl_xor(pr1, 32);

      if (SCATTER_MODE == 0) {
        if (h == 0 && validC)
          ((unsigned*)out_ch)[(size_t)pos * 8 + mt] = packc(pr0, pr1);
      } else {
        if (h == 0 && validC) {
          float* sums = (float*)out_ch;
          atomicAdd(&sums[(size_t)oeC * 16 + 2 * mt],     pr0);
          atomicAdd(&sums[(size_t)oeC * 16 + 2 * mt + 1], pr1);
        }
      }
    }
    if (SCATTER_MODE == 1) {
      if (h == 0 && validC) atomicAdd(&aux[oeC], 1);
    }

    // ---- rotate pipeline state ----
    bhC[0] = bhN[0]; bhC[1] = bhN[1]; bhC[2] = bhN[2]; bhC[3] = bhN[3];
    f4aC = f4aN; f4bC = f4bN; oeC = oeN; validC = validN;
    ieN = ieNN; oeN = oeNN; validN = validNN;
    xN0 = xNN0; xN1 = xNN1; xN2 = xNN2;
  }
}

// ---------------- per-node reduce (CSR path, bf16 rows; R17-verified) ----------------

__global__ __launch_bounds__(256)
void nf_reduce(const uint4v* __restrict__ out_chb4, const int* __restrict__ counts,
               const int* __restrict__ offsets, float* __restrict__ out, int N) {
  const int gid  = blockIdx.x * 128 + (threadIdx.x >> 1);  // node
  const int half = threadIdx.x & 1;                        // channels 8h..8h+7
  if (gid >= N) return;
  const int deg = counts[gid];
  const int off = offsets[gid];
  float a[8] = {0.f, 0.f, 0.f, 0.f, 0.f, 0.f, 0.f, 0.f};
  for (int d = 0; d < deg; ++d) {
    const uint4v u = out_chb4[(size_t)(off + d) * 2 + half];
#pragma unroll
    for (int p = 0; p < 4; ++p) {
      a[2 * p]     += bflo2f(u[p]);
      a[2 * p + 1] += bfhi2f(u[p]);
    }
  }
  const float inv = 1.0f / fmaxf((float)deg, 1.0f);
  float4v r0, r1;
#pragma unroll
  for (int p = 0; p < 4; ++p) { r0[p] = a[p] * inv; r1[p] = a[4 + p] * inv; }
  float* dst = out + (size_t)gid * 16 + 8 * half;
  *(float4v*)dst       = r0;
  *(float4v*)(dst + 4) = r1;
}

// fallback divide
__global__ void nf_final(float* __restrict__ out, const int* __restrict__ counts, int n) {
  int i = blockIdx.x * blockDim.x + threadIdx.x;
  if (i < n) {
    float c = (float)counts[i >> 4];
    out[i] = out[i] / fmaxf(c, 1.0f);
  }
}

extern "C" void kernel_launch(void* const* d_in, const int* in_sizes, int n_in,
                              void* d_out, int out_size, void* d_ws, size_t ws_size,
                              hipStream_t stream) {
  const int*   in_edges  = (const int*)d_in[0];
  const int*   out_edges = (const int*)d_in[1];
  const float* ef        = (const float*)d_in[2];
  const float* coords    = (const float*)d_in[3];
  const float* W1  = (const float*)d_in[4];
  const float* b1  = (const float*)d_in[5];
  const float* g1  = (const float*)d_in[6];
  const float* be1 = (const float*)d_in[7];
  const float* W2  = (const float*)d_in[8];
  const float* b2  = (const float*)d_in[9];
  const float* g2  = (const float*)d_in[10];
  const float* be2 = (const float*)d_in[11];
  const float* W3  = (const float*)d_in[12];
  const float* b3  = (const float*)d_in[13];

  const int E = in_sizes[0];
  const int N = in_sizes[2] / 16;
  const int ntiles = (E + 31) / 32;
  float* out = (float*)d_out;

  // ws: out_chb [8E u32 bf16x2] | counts [N] | total [1] | offsets [N] | cursor [N]
  const size_t need = ((size_t)E * 8 + 3 * (size_t)N + 1) * 4;

  if (ws_size >= need) {
    unsigned* out_chb = (unsigned*)d_ws;
    int*      counts  = (int*)(out_chb + (size_t)E * 8);
    int*      total   = counts + N;
    int*      offsets = total + 1;
    int*      cursor  = offsets + N;

    (void)hipMemsetAsync(counts, 0, ((size_t)N + 1) * sizeof(int), stream);
    nf_hist<<<(E / 4 + 255) / 256 + 1, 256, 0, stream>>>(out_edges, counts, E);
    nf_alloc<<<(N + 255) / 256, 256, 0, stream>>>(counts, offsets, cursor, total, N);
    nf_main<0><<<1536, 256, 0, stream>>>(in_edges, out_edges, ef, coords,
                                         W1, b1, g1, be1, W2, b2, g2, be2, W3, b3,
                                         out_chb, nullptr, cursor, E, ntiles);
    nf_reduce<<<(N + 127) / 128, 256, 0, stream>>>((const uint4v*)out_chb, counts,
                                                   offsets, out, N);
  } else {
    // fallback: direct f32 atomics
    int* counts = (int*)d_ws;
    (void)hipMemsetAsync(out, 0, (size_t)out_size * sizeof(float), stream);
    (void)hipMemsetAsync(counts, 0, (size_t)N * sizeof(int), stream);
    nf_main<1><<<1536, 256, 0, stream>>>(in_edges, out_edges, ef, coords,
                                         W1, b1, g1, be1, W2, b2, g2, be2, W3, b3,
                                         out, counts, nullptr, E, ntiles);
    nf_final<<<(out_size + 255) / 256, 256, 0, stream>>>(out, counts, out_size);
  }
}

// Round 23
// 171.027 us; speedup vs baseline: 3.1189x; 1.0061x over previous
//
#include <hip/hip_runtime.h>
#include <hip/hip_bf16.h>

// NeuralFieldCosmo — R23: R22 byte-identical kernels; ONE change: nf_main
// grid 1536 -> 2048 (8 blocks/CU). R22's skew restructure dropped VGPR
// 84 -> 52, crossing the 64-VGPR band boundary (waves/SIMD halve at
// 64/128/256 — R21 lesson): the <=64 band admits 8 waves/SIMD. LDS
// 8 x 18.4KB = 147KB <= 160KB. Kernel latency-bound (VALU 55%, MFMA 12.5%,
// HBM 6%) -> +33% resident waves = +33% independent chains.
// Ledger: raw cvt_pk asm banned. f2bf + packc verified. 32x32x8 A/B/C
// layouts verified R18-R22. unroll-1 epilogue = spill fix. Spill tell =
// FETCH > 150 MB. Pre-commit: null result -> declare roofline next round.

typedef __attribute__((ext_vector_type(4)))  short    short4v;  // 4 bf16 (2 VGPR)
typedef __attribute__((ext_vector_type(4)))  float    float4v;
typedef __attribute__((ext_vector_type(16))) float    f32x16;
typedef __attribute__((ext_vector_type(4)))  unsigned uint4v;
typedef __attribute__((ext_vector_type(2)))  unsigned uint2v;

constexpr float LN_EPS   = 1e-5f;
constexpr float LOG2E_X2 = 2.8853900817779268f;  // 2*log2(e)

// RNE float -> bf16 bits (staging; verified R4-R22)
__device__ __forceinline__ unsigned f2bf(float x) {
  unsigned u = __builtin_bit_cast(unsigned, x);
  u += 0x7FFFu + ((u >> 16) & 1u);
  return u >> 16;
}
__device__ __forceinline__ unsigned pack2(float lo, float hi) {
  return f2bf(lo) | (f2bf(hi) << 16);
}
// HOT pack: library bf16x2 cvt (RNE), low 16 bits = lo. Verified R16-R22.
__device__ __forceinline__ unsigned packc(float lo, float hi) {
  float2 v; v.x = lo; v.y = hi;
  const __hip_bfloat162 b = __float22bfloat162_rn(v);
  static_assert(sizeof(__hip_bfloat162) == 4, "bf16x2 must be 4 bytes");
  unsigned r;
  __builtin_memcpy(&r, &b, 4);
  return r;
}
__device__ __forceinline__ float bflo2f(unsigned u) {
  return __builtin_bit_cast(float, u << 16);
}
__device__ __forceinline__ float bfhi2f(unsigned u) {
  return __builtin_bit_cast(float, u & 0xFFFF0000u);
}
// rcp(exp2(x)+1)
__device__ __forceinline__ float sigm2(float x) {
  return __builtin_amdgcn_rcpf(__builtin_amdgcn_exp2f(x) + 1.0f);
}

__device__ __forceinline__ f32x16 mfma32(short4v a, short4v b, f32x16 c) {
#if __has_builtin(__builtin_amdgcn_mfma_f32_32x32x8bf16_1k)
  return __builtin_amdgcn_mfma_f32_32x32x8bf16_1k(a, b, c, 0, 0, 0);
#else
  asm volatile("v_mfma_f32_32x32x8_bf16 %0, %1, %2, %0\n\ts_nop 7\n\ts_nop 7"
               : "+v"(c) : "v"(a), "v"(b));
  return c;
#endif
}

// LN over 32 chs (16/lane; lane^32 holds complement), affine from f32 LDS
// (broadcast reads), relu, pack to 4 B-frag K-segments via packc.
__device__ __forceinline__ void ln_relu_pack32f(const float* hv,
                                                const float* __restrict__ gf,
                                                const float* __restrict__ bef,
                                                short4v* bh) {
  float sum = 0.f, ss = 0.f;
#pragma unroll
  for (int i = 0; i < 16; ++i) { sum += hv[i]; ss += hv[i] * hv[i]; }
  sum += __shfl_xor(sum, 32);
  ss  += __shfl_xor(ss, 32);
  const float m   = sum * (1.0f / 32.0f);
  const float var = fmaxf(ss * (1.0f / 32.0f) - m * m, 0.f);
  const float rs  = rsqrtf(var + LN_EPS);
#pragma unroll
  for (int s = 0; s < 4; ++s) {
    const float4v gv = *(const float4v*)&gf[s * 4];
    const float4v bv = *(const float4v*)&bef[s * 4];
    float y[4];
#pragma unroll
    for (int j = 0; j < 4; ++j)
      y[j] = fmaxf((hv[s * 4 + j] - m) * rs * gv[j] + bv[j], 0.f);
    uint2v u; u[0] = packc(y[0], y[1]); u[1] = packc(y[2], y[3]);
    bh[s] = __builtin_bit_cast(short4v, u);
  }
}

// ---------------- CSR build (R17-verified) ----------------

__global__ void nf_hist(const int* __restrict__ out_edges, int* __restrict__ counts, int E) {
  const int t4 = (blockIdx.x * blockDim.x + threadIdx.x) * 4;
  if (t4 + 3 < E) {
    const int4 v = *(const int4*)(out_edges + t4);
    atomicAdd(&counts[v.x], 1);
    atomicAdd(&counts[v.y], 1);
    atomicAdd(&counts[v.z], 1);
    atomicAdd(&counts[v.w], 1);
  } else {
    for (int i = t4; i < E; ++i) atomicAdd(&counts[out_edges[i]], 1);
  }
}

__global__ void nf_alloc(const int* __restrict__ counts, int* __restrict__ offsets,
                         int* __restrict__ cursor, int* __restrict__ total, int N) {
  const int i = blockIdx.x * blockDim.x + threadIdx.x;
  const int lane = threadIdx.x & 63;
  int c = (i < N) ? counts[i] : 0;
  int sc = c;
#pragma unroll
  for (int d = 1; d < 64; d <<= 1) {
    int v = __shfl_up(sc, d);
    if (lane >= d) sc += v;
  }
  const int excl = sc - c;
  const int wtot = __shfl(sc, 63);
  int base = 0;
  if (lane == 0) base = atomicAdd(total, wtot);
  base = __shfl(base, 0);
  if (i < N) {
    offsets[i] = base + excl;
    cursor[i]  = base + excl;
  }
}

// ---------------- main compute ----------------
// SCATTER_MODE: 0 = CSR-ordered bf16 stream, 1 = direct f32 atomics fallback

template <int SCATTER_MODE>
__global__ __launch_bounds__(256, 2)
void nf_main(const int* __restrict__ in_edges,
             const int* __restrict__ out_edges,
             const float* __restrict__ ef,
             const float* __restrict__ coords,
             const float* __restrict__ W1, const float* __restrict__ b1,
             const float* __restrict__ g1, const float* __restrict__ be1,
             const float* __restrict__ W2, const float* __restrict__ b2,
             const float* __restrict__ g2, const float* __restrict__ be2,
             const float* __restrict__ W3, const float* __restrict__ b3,
             void* __restrict__ out_ch,   // mode0: unsigned[E][8] bf16x2 ; mode1: float sums (d_out)
             int* __restrict__ aux,       // mode1: counts
             int* __restrict__ cursor,    // mode0: [N]
             int E, int ntiles)
{
  // W3 A-frags (prescaled 2log2e): [mt][blk][lane][4 u32]  (16 KB)
  __shared__ __align__(16) unsigned sA3[8 * 2 * 64 * 4];
  __shared__ __align__(16) float    sB3f[256];     // 2log2e*b3, [o][i]
  __shared__ __align__(16) float    sB2f[2][16];   // b2 in C-row order
  // f32 per-h lane-channel consts, hv order (idx s*4+j <-> ch 8s+4h+j)
  __shared__ __align__(16) float    sB1f[2][16];
  __shared__ __align__(16) float    sG1[2][16],  sBe1[2][16];
  __shared__ __align__(16) float    sG2[2][16],  sBe2[2][16];

  const int t    = threadIdx.x;
  const int l    = t & 63;
  const int h    = l >> 5;     // half: k-group / C-row group
  const int ecol = l & 31;     // edge column within 32-edge tile

  // ---- one-time LDS staging (R18-R22 verified) ----
#pragma unroll
  for (int rep = 0; rep < 16; ++rep) {
    const int idx = rep * 256 + t;
    const int u = idx & 3, ll = (idx >> 2) & 63, b = (idx >> 8) & 1, mt = idx >> 9;
    const int s = b * 2 + (u >> 1), jp = u & 1;
    const int hh = ll >> 5, m = ll & 31;
    const int o = 2 * mt + (m >> 4), i = m & 15;
    const int k0 = 8 * s + 4 * hh + 2 * jp;
    sA3[idx] = pack2(LOG2E_X2 * W3[(size_t)k0 * 256 + o * 16 + i],
                     LOG2E_X2 * W3[(size_t)(k0 + 1) * 256 + o * 16 + i]);
  }
  sB3f[t] = LOG2E_X2 * b3[t];
  if (t < 32) {
    const int hh = t >> 4, r = t & 15;          // r = s*4+j
    const int ch = 8 * (r >> 2) + 4 * hh + (r & 3);
    sB2f[hh][r] = b2[ch];
    sB1f[hh][r] = b1[ch];
    sG1[hh][r]  = g1[ch];   sBe1[hh][r] = be1[ch];
    sG2[hh][r]  = g2[ch];   sBe2[hh][r] = be2[ch];
  }

  // L1 A-frag: A[m=ch_out=ecol][k=4h+j] = W1[k][ecol], k<3
  short4v a1;
#pragma unroll
  for (int j = 0; j < 4; ++j) {
    const int k = 4 * h + j;
    a1[j] = (k < 3) ? (short)f2bf(W1[k * 32 + ecol]) : (short)0;
  }
  // L2 A-frags (8 VGPR): A[m=ecol][k=8s+4h+j] = W2[k][ecol]
  short4v a2[4];
#pragma unroll
  for (int s = 0; s < 4; ++s) {
    short4v v;
#pragma unroll
    for (int j = 0; j < 4; ++j)
      v[j] = (short)f2bf(W2[(8 * s + 4 * h + j) * 32 + ecol]);
    a2[s] = v;
  }
  __syncthreads();

  // front: L1-MFMA -> LN1 -> L2 -> LN2 -> bh[4] (R20-R22 numerics)
  auto front = [&](float x0, float x1, float x2, short4v* bh) {
    short4v bx;
    {
      uint2v u;
      u[0] = h ? 0u : packc(x0, x1);
      u[1] = h ? 0u : packc(x2, 0.f);
      bx = __builtin_bit_cast(short4v, u);
    }
    f32x16 c;
    {
      const float4v* bb = (const float4v*)&sB1f[h][0];
      const float4v i0 = bb[0], i1 = bb[1], i2 = bb[2], i3 = bb[3];
#pragma unroll
      for (int e = 0; e < 4; ++e) {
        c[e] = i0[e]; c[4 + e] = i1[e]; c[8 + e] = i2[e]; c[12 + e] = i3[e];
      }
    }
    c = mfma32(a1, bx, c);

    float hv[16];
#pragma unroll
    for (int r = 0; r < 16; ++r) hv[r] = c[r];
    ln_relu_pack32f(hv, &sG1[h][0], &sBe1[h][0], bh);

    {
      const float4v* bb = (const float4v*)&sB2f[h][0];
      const float4v i0 = bb[0], i1 = bb[1], i2 = bb[2], i3 = bb[3];
#pragma unroll
      for (int e = 0; e < 4; ++e) {
        c[e] = i0[e]; c[4 + e] = i1[e]; c[8 + e] = i2[e]; c[12 + e] = i3[e];
      }
    }
#pragma unroll
    for (int s = 0; s < 4; ++s) c = mfma32(a2[s], bh[s], c);

#pragma unroll
    for (int r = 0; r < 16; ++r) hv[r] = c[r];
    ln_relu_pack32f(hv, &sG2[h][0], &sBe2[h][0], bh);
  };

  const int gwave  = (blockIdx.x * blockDim.x + t) >> 6;
  const int nwaves = (gridDim.x * blockDim.x) >> 6;

  // ---- skewed-pipeline prologue ----
  int tile = gwave;
  bool validC = false; int oeC = 0;
  short4v bhC[4] = {};
  float4v f4aC = {}, f4bC = {};
  bool validN = false; int ieN = 0, oeN = 0;
  float xN0 = 0.f, xN1 = 0.f, xN2 = 0.f;

  if (tile < ntiles) {
    const int eIdx = tile * 32 + ecol;
    validC = eIdx < E;
    const int eS = validC ? eIdx : 0;
    const int ie = in_edges[eS]; oeC = out_edges[eS];
    const float x0 = coords[3 * eS], x1 = coords[3 * eS + 1], x2 = coords[3 * eS + 2];
    f4aC = *(const float4v*)(ef + (size_t)ie * 16 + 4 * h);
    f4bC = *(const float4v*)(ef + (size_t)ie * 16 + 8 + 4 * h);
    front(x0, x1, x2, bhC);
  }
  if (tile + nwaves < ntiles) {
    const int eIdx = (tile + nwaves) * 32 + ecol;
    validN = eIdx < E;
    const int eS = validN ? eIdx : 0;
    ieN = in_edges[eS]; oeN = out_edges[eS];
    xN0 = coords[3 * eS]; xN1 = coords[3 * eS + 1]; xN2 = coords[3 * eS + 2];
  }

  for (; tile < ntiles; tile += nwaves) {
    const int tn  = tile + nwaves;       // tile whose front runs this iter
    const int tnn = tile + 2 * nwaves;   // tile whose idx/coords prefetch now

    // ---- issue next tile's feature gathers (consumed next iteration) ----
    float4v f4aN = {}, f4bN = {};
    if (tn < ntiles) {
      f4aN = *(const float4v*)(ef + (size_t)ieN * 16 + 4 * h);
      f4bN = *(const float4v*)(ef + (size_t)ieN * 16 + 8 + 4 * h);
    }

    // CSR slot for CURRENT tile (latency hides under front+epilogue)
    int pos = 0;
    if (SCATTER_MODE == 0 && h == 0 && validC)
      pos = atomicAdd(&cursor[oeC], 1);

    // ---- prefetch tile t+2 idx/coords ----
    bool validNN = false; int ieNN = 0, oeNN = 0;
    float xNN0 = 0.f, xNN1 = 0.f, xNN2 = 0.f;
    if (tnn < ntiles) {
      const int eIdx = tnn * 32 + ecol;
      validNN = eIdx < E;
      const int eS = validNN ? eIdx : 0;
      ieNN = in_edges[eS]; oeNN = out_edges[eS];
      xNN0 = coords[3 * eS]; xNN1 = coords[3 * eS + 1]; xNN2 = coords[3 * eS + 2];
    }

    // ---- front(t+1): serial MFMA/LN chains issue first... ----
    short4v bhN[4] = {};
    if (tn < ntiles)
      front(xN0, xN1, xN2, bhN);

    // ---- ...epilogue(t): independent trans/FMA stream fills the stalls ----
    const float sumf = (f4aC[0] + f4aC[1]) + (f4aC[2] + f4aC[3])
                     + (f4bC[0] + f4bC[1]) + (f4bC[2] + f4bC[3]);

    // unroll 1: bounds scheduler load-hoisting (R18 spill, R19 fix)
#pragma unroll 1
    for (int mt = 0; mt < 8; ++mt) {
      const uint4v av0 = *(const uint4v*)&sA3[mt * 512 + (l << 2)];
      const uint4v av1 = *(const uint4v*)&sA3[mt * 512 + 256 + (l << 2)];
      f32x16 c3;
      {
        const float4v i0 = *(const float4v*)&sB3f[(2 * mt) * 16 + 4 * h];
        const float4v i1 = *(const float4v*)&sB3f[(2 * mt) * 16 + 8 + 4 * h];
        const float4v i2 = *(const float4v*)&sB3f[(2 * mt + 1) * 16 + 4 * h];
        const float4v i3 = *(const float4v*)&sB3f[(2 * mt + 1) * 16 + 8 + 4 * h];
#pragma unroll
        for (int e = 0; e < 4; ++e) {
          c3[e] = i0[e]; c3[4 + e] = i1[e]; c3[8 + e] = i2[e]; c3[12 + e] = i3[e];
        }
      }
      uint2v u01, u23;
      u01[0] = av0[0]; u01[1] = av0[1];  u23[0] = av0[2]; u23[1] = av0[3];
      c3 = mfma32(__builtin_bit_cast(short4v, u01), bhC[0], c3);
      c3 = mfma32(__builtin_bit_cast(short4v, u23), bhC[1], c3);
      u01[0] = av1[0]; u01[1] = av1[1];  u23[0] = av1[2]; u23[1] = av1[3];
      c3 = mfma32(__builtin_bit_cast(short4v, u01), bhC[2], c3);
      c3 = mfma32(__builtin_bit_cast(short4v, u23), bhC[3], c3);

      float dot0 = 0.f, dot1 = 0.f;
#pragma unroll
      for (int j = 0; j < 4; ++j) {
        dot0 = fmaf(f4aC[j], sigm2(c3[j]),      dot0);
        dot0 = fmaf(f4bC[j], sigm2(c3[4 + j]),  dot0);
        dot1 = fmaf(f4aC[j], sigm2(c3[8 + j]),  dot1);
        dot1 = fmaf(f4bC[j], sigm2(c3[12 + j]), dot1);
      }
      float pr0 = fmaf(-2.0f, dot0, sumf);
      float pr1 = fmaf(-2.0f, dot1, sumf);
      pr0 += __shfl_xor(pr0, 32);
      pr1 += __shfl_xor(pr1, 32);

      if (SCATTER_MODE == 0) {
        if (h == 0 && validC)
          ((unsigned*)out_ch)[(size_t)pos * 8 + mt] = packc(pr0, pr1);
      } else {
        if (h == 0 && validC) {
          float* sums = (float*)out_ch;
          atomicAdd(&sums[(size_t)oeC * 16 + 2 * mt],     pr0);
          atomicAdd(&sums[(size_t)oeC * 16 + 2 * mt + 1], pr1);
        }
      }
    }
    if (SCATTER_MODE == 1) {
      if (h == 0 && validC) atomicAdd(&aux[oeC], 1);
    }

    // ---- rotate pipeline state ----
    bhC[0] = bhN[0]; bhC[1] = bhN[1]; bhC[2] = bhN[2]; bhC[3] = bhN[3];
    f4aC = f4aN; f4bC = f4bN; oeC = oeN; validC = validN;
    ieN = ieNN; oeN = oeNN; validN = validNN;
    xN0 = xNN0; xN1 = xNN1; xN2 = xNN2;
  }
}

// ---------------- per-node reduce (CSR path, bf16 rows; R17-verified) ----------------

__global__ __launch_bounds__(256)
void nf_reduce(const uint4v* __restrict__ out_chb4, const int* __restrict__ counts,
               const int* __restrict__ offsets, float* __restrict__ out, int N) {
  const int gid  = blockIdx.x * 128 + (threadIdx.x >> 1);  // node
  const int half = threadIdx.x & 1;                        // channels 8h..8h+7
  if (gid >= N) return;
  const int deg = counts[gid];
  const int off = offsets[gid];
  float a[8] = {0.f, 0.f, 0.f, 0.f, 0.f, 0.f, 0.f, 0.f};
  for (int d = 0; d < deg; ++d) {
    const uint4v u = out_chb4[(size_t)(off + d) * 2 + half];
#pragma unroll
    for (int p = 0; p < 4; ++p) {
      a[2 * p]     += bflo2f(u[p]);
      a[2 * p + 1] += bfhi2f(u[p]);
    }
  }
  const float inv = 1.0f / fmaxf((float)deg, 1.0f);
  float4v r0, r1;
#pragma unroll
  for (int p = 0; p < 4; ++p) { r0[p] = a[p] * inv; r1[p] = a[4 + p] * inv; }
  float* dst = out + (size_t)gid * 16 + 8 * half;
  *(float4v*)dst       = r0;
  *(float4v*)(dst + 4) = r1;
}

// fallback divide
__global__ void nf_final(float* __restrict__ out, const int* __restrict__ counts, int n) {
  int i = blockIdx.x * blockDim.x + threadIdx.x;
  if (i < n) {
    float c = (float)counts[i >> 4];
    out[i] = out[i] / fmaxf(c, 1.0f);
  }
}

extern "C" void kernel_launch(void* const* d_in, const int* in_sizes, int n_in,
                              void* d_out, int out_size, void* d_ws, size_t ws_size,
                              hipStream_t stream) {
  const int*   in_edges  = (const int*)d_in[0];
  const int*   out_edges = (const int*)d_in[1];
  const float* ef        = (const float*)d_in[2];
  const float* coords    = (const float*)d_in[3];
  const float* W1  = (const float*)d_in[4];
  const float* b1  = (const float*)d_in[5];
  const float* g1  = (const float*)d_in[6];
  const float* be1 = (const float*)d_in[7];
  const float* W2  = (const float*)d_in[8];
  const float* b2  = (const float*)d_in[9];
  const float* g2  = (const float*)d_in[10];
  const float* be2 = (const float*)d_in[11];
  const float* W3  = (const float*)d_in[12];
  const float* b3  = (const float*)d_in[13];

  const int E = in_sizes[0];
  const int N = in_sizes[2] / 16;
  const int ntiles = (E + 31) / 32;
  float* out = (float*)d_out;

  // ws: out_chb [8E u32 bf16x2] | counts [N] | total [1] | offsets [N] | cursor [N]
  const size_t need = ((size_t)E * 8 + 3 * (size_t)N + 1) * 4;

  if (ws_size >= need) {
    unsigned* out_chb = (unsigned*)d_ws;
    int*      counts  = (int*)(out_chb + (size_t)E * 8);
    int*      total   = counts + N;
    int*      offsets = total + 1;
    int*      cursor  = offsets + N;

    (void)hipMemsetAsync(counts, 0, ((size_t)N + 1) * sizeof(int), stream);
    nf_hist<<<(E / 4 + 255) / 256 + 1, 256, 0, stream>>>(out_edges, counts, E);
    nf_alloc<<<(N + 255) / 256, 256, 0, stream>>>(counts, offsets, cursor, total, N);
    nf_main<0><<<2048, 256, 0, stream>>>(in_edges, out_edges, ef, coords,
                                         W1, b1, g1, be1, W2, b2, g2, be2, W3, b3,
                                         out_chb, nullptr, cursor, E, ntiles);
    nf_reduce<<<(N + 127) / 128, 256, 0, stream>>>((const uint4v*)out_chb, counts,
                                                   offsets, out, N);
  } else {
    // fallback: direct f32 atomics
    int* counts = (int*)d_ws;
    (void)hipMemsetAsync(out, 0, (size_t)out_size * sizeof(float), stream);
    (void)hipMemsetAsync(counts, 0, (size_t)N * sizeof(int), stream);
    nf_main<1><<<2048, 256, 0, stream>>>(in_edges, out_edges, ef, coords,
                                         W1, b1, g1, be1, W2, b2, g2, be2, W3, b3,
                                         out, counts, nullptr, E, ntiles);
    nf_final<<<(out_size + 255) / 256, 256, 0, stream>>>(out, counts, out_size);
  }
}